// Round 5
// baseline (1116.635 us; speedup 1.0000x reference)
//
#include <hip/hip_runtime.h>
#include <hip/hip_bf16.h>

#define NN 500000
#define NE 8000000
#define NB 123           // buckets of 4096 nodes: 123*4096 = 503808 >= NN
#define BSH 12
#define BSZ 4096
#define CAP 69632        // fixed bucket capacity (65536 mean + 16 sigma), mult of 4
#define M 8              // slices (blocks) per bucket
#define NAGG (NB * M)    // 984 blocks
#define BN_EPS 1e-5f

typedef unsigned uv4 __attribute__((ext_vector_type(4)));
typedef int iv4 __attribute__((ext_vector_type(4)));
typedef float fv4 __attribute__((ext_vector_type(4)));
typedef unsigned long long u64;

__device__ __forceinline__ float waveReduceF(float v) {
#pragma unroll
    for (int o = 32; o > 0; o >>= 1) v += __shfl_down(v, o, 64);
    return v;
}
__device__ __forceinline__ double waveReduceD(double v) {
#pragma unroll
    for (int o = 32; o > 0; o >>= 1) v += __shfl_down(v, o, 64);
    return v;
}
__device__ __forceinline__ float u2f(unsigned short u) {
    return __bfloat162float(__builtin_bit_cast(__hip_bfloat16, u));
}
__device__ __forceinline__ unsigned short f2u(float f) {
    return __builtin_bit_cast(unsigned short, __float2bfloat16(f));
}
// pack x-sample into (fixed<<20)+count1.  |x|<6 -> x*2^28 < 2^31 (int ok)
__device__ __forceinline__ u64 pk1(float v) {
    int iv = (int)rintf(v * 268435456.f);              // 2^28
    return ((u64)(long long)iv << 20) + 1ull;
}

// ---------------- bucketize: block counting sort, coalesced emit ---------------
__global__ __launch_bounds__(512) void scatterk(
    const iv4* __restrict__ src4, const iv4* __restrict__ dst4,
    const fv4* __restrict__ w4, int* __restrict__ cur,
    unsigned* __restrict__ pairs, unsigned short* __restrict__ wp)
{
    __shared__ unsigned sEnt[4096];        // 16 KB
    __shared__ unsigned short sW[4096];    // 8 KB
    __shared__ unsigned char sB[4096];     // 4 KB
    __shared__ int h[8][128];              // per-wave histograms
    __shared__ int wOff[8][128];           // cross-wave prefix per bucket
    __shared__ int bOff[128];              // block-local bucket prefix
    __shared__ int lb[128];                // global base for this block per bucket
    __shared__ int tot[128];

    int tid = threadIdx.x, wv = tid >> 6;
    for (int j = tid; j < 8 * 128; j += 512) (&h[0][0])[j] = 0;
    __syncthreads();

    unsigned en[8]; unsigned short wb[8]; int rb[8];   // rk<<8 | b, or -1
#pragma unroll
    for (int k = 0; k < 2; k++) {
        int q = blockIdx.x * 1024 + k * 512 + tid;
        if (q < NE / 4) {
            iv4 s4 = __builtin_nontemporal_load(src4 + q);
            iv4 d4 = __builtin_nontemporal_load(dst4 + q);
            fv4 ww = __builtin_nontemporal_load(w4 + q);
            int ss[4] = {s4.x, s4.y, s4.z, s4.w};
            int dd[4] = {d4.x, d4.y, d4.z, d4.w};
            float fw[4] = {ww.x, ww.y, ww.z, ww.w};
#pragma unroll
            for (int i = 0; i < 4; i++) {
                int d = dd[i], b = d >> BSH;
                en[k * 4 + i] = ((unsigned)(d & (BSZ - 1)) << 19) | (unsigned)ss[i];
                wb[k * 4 + i] = f2u(fw[i]);
                int rk = atomicAdd(&h[wv][b], 1);
                rb[k * 4 + i] = (rk << 8) | b;
            }
        } else {
#pragma unroll
            for (int i = 0; i < 4; i++) rb[k * 4 + i] = -1;
        }
    }
    __syncthreads();
    if (tid < NB) {
        int acc = 0;
#pragma unroll
        for (int w = 0; w < 8; w++) { wOff[w][tid] = acc; acc += h[w][tid]; }
        tot[tid] = acc;
        lb[tid] = tid * CAP + atomicAdd(&cur[tid], acc);
    }
    __syncthreads();
    // wave-parallel exclusive prefix of tot -> bOff (lanes 0..63, 2 elems each)
    if (tid < 64) {
        int lane = tid;
        int a = (2 * lane < NB) ? tot[2 * lane] : 0;
        int b = (2 * lane + 1 < NB) ? tot[2 * lane + 1] : 0;
        int s = a + b;
#pragma unroll
        for (int o = 1; o < 64; o <<= 1) {
            int t = __shfl_up(s, o, 64);
            if (lane >= o) s += t;
        }
        int excl = s - (a + b);
        bOff[2 * lane] = excl;
        bOff[2 * lane + 1] = excl + a;
    }
    __syncthreads();
#pragma unroll
    for (int k = 0; k < 8; k++) {
        if (rb[k] >= 0) {
            int b = rb[k] & 255, rk = rb[k] >> 8;
            int pos = bOff[b] + wOff[wv][b] + rk;
            sEnt[pos] = en[k]; sW[pos] = wb[k]; sB[pos] = (unsigned char)b;
        }
    }
    __syncthreads();
    int nE = NE - blockIdx.x * 4096; if (nE > 4096) nE = 4096;
    for (int j = tid; j < nE; j += 512) {
        int b = sB[j];
        int glob = lb[b] + (j - bOff[b]);
        __builtin_nontemporal_store(sEnt[j], pairs + glob);
        __builtin_nontemporal_store(sW[j], wp + glob);
    }
}

// ---------------- agg pass 1: packed u64 atomics, natural pipelining,
//                  last-slice-per-bucket merges slabs -> UN2 + ENC -------------
__global__ __launch_bounds__(512) void agg1k(
    const unsigned* __restrict__ pairs, const int* __restrict__ cur,
    const float* __restrict__ x, u64* __restrict__ slab, int* __restrict__ cnt1,
    float2* __restrict__ UN2, u64* __restrict__ ENC)
{
    __shared__ u64 t[BSZ];   // 32 KB
    __shared__ int lastS;
    for (int j = threadIdx.x; j < BSZ; j += 512) t[j] = 0ull;
    __syncthreads();
    int B = blockIdx.x / M, sl = blockIdx.x % M;
    int b0 = B * CAP;
    int len = cur[B];
    int seg = (((len + M - 1) / M) + 3) & ~3;
    int lo = b0 + sl * seg;
    int hi = lo + seg, e1 = b0 + len;
    if (hi > e1) hi = e1;
    int n = hi - lo;
    if (n > 0) {
        int nq = n >> 2;
        const uv4* pq = (const uv4*)(pairs + lo);
        for (int i = threadIdx.x; i < nq; i += 1024) {
            uv4 pA = __builtin_nontemporal_load(pq + i);
            int iB = i + 512;
            bool vB = iB < nq;
            float a0 = x[pA.x & 524287u];
            float a1 = x[pA.y & 524287u];
            float a2 = x[pA.z & 524287u];
            float a3 = x[pA.w & 524287u];
            float c0, c1, c2, c3; unsigned d4, d5, d6, d7;
            if (vB) {
                uv4 pB = __builtin_nontemporal_load(pq + iB);
                c0 = x[pB.x & 524287u]; d4 = pB.x >> 19;
                c1 = x[pB.y & 524287u]; d5 = pB.y >> 19;
                c2 = x[pB.z & 524287u]; d6 = pB.z >> 19;
                c3 = x[pB.w & 524287u]; d7 = pB.w >> 19;
            }
            atomicAdd(&t[pA.x >> 19], pk1(a0));
            atomicAdd(&t[pA.y >> 19], pk1(a1));
            atomicAdd(&t[pA.z >> 19], pk1(a2));
            atomicAdd(&t[pA.w >> 19], pk1(a3));
            if (vB) {
                atomicAdd(&t[d4], pk1(c0));
                atomicAdd(&t[d5], pk1(c1));
                atomicAdd(&t[d6], pk1(c2));
                atomicAdd(&t[d7], pk1(c3));
            }
        }
        int rem = n & 3;
        if ((int)threadIdx.x < rem) {
            unsigned p = pairs[lo + (nq << 2) + threadIdx.x];
            atomicAdd(&t[p >> 19], pk1(x[p & 524287u]));
        }
    }
    __syncthreads();
    u64* sb = slab + (size_t)blockIdx.x * BSZ;
    for (int j = threadIdx.x; j < BSZ; j += 512) sb[j] = t[j];
    // release own stores, then count this slice done
    __threadfence();
    __syncthreads();
    if (threadIdx.x == 0)
        lastS = (atomicAdd(&cnt1[B], 1) == M - 1) ? 1 : 0;
    __syncthreads();
    if (lastS) {
        // merge the 8 slices of bucket B -> UN2 + ENC (decode fixed-point)
        int base = B << BSH;
        for (int j = threadIdx.x; j < BSZ; j += 512) {
            int node = base + j;
            if (node >= NN) continue;
            u64 s = 0ull;
#pragma unroll
            for (int m = 0; m < M; m++)
                s += __hip_atomic_load(&slab[(size_t)(B * M + m) * BSZ + j],
                                       __ATOMIC_RELAXED, __HIP_MEMORY_SCOPE_AGENT);
            unsigned cn = (unsigned)(s & 0xFFFFFull);
            long long sv = (long long)(s - (u64)cn) >> 20;
            float u = x[node] + (float)((double)sv * 3.725290298461914e-09);  // 2^-28
            UN2[node] = make_float2(u, (float)cn);
            long long iu = (long long)rintf(u * 67108864.f);                  // 2^26
            ENC[node] = ((u64)iu << 22) + (u64)cn;
        }
    }
}

// ---------------- agg pass 2: gather pre-packed ENC, fused merge -> SU/SN ------
__global__ __launch_bounds__(512) void agg2k(
    const unsigned* __restrict__ pairs, const int* __restrict__ cur,
    const u64* __restrict__ ENC, u64* __restrict__ slab, int* __restrict__ cnt2,
    float* __restrict__ SU, float* __restrict__ SN)
{
    __shared__ u64 t[BSZ];   // 32 KB
    __shared__ int lastS;
    for (int j = threadIdx.x; j < BSZ; j += 512) t[j] = 0ull;
    __syncthreads();
    int B = blockIdx.x / M, sl = blockIdx.x % M;
    int b0 = B * CAP;
    int len = cur[B];
    int seg = (((len + M - 1) / M) + 3) & ~3;
    int lo = b0 + sl * seg;
    int hi = lo + seg, e1 = b0 + len;
    if (hi > e1) hi = e1;
    int n = hi - lo;
    if (n > 0) {
        int nq = n >> 2;
        const uv4* pq = (const uv4*)(pairs + lo);
        for (int i = threadIdx.x; i < nq; i += 1024) {
            uv4 pA = __builtin_nontemporal_load(pq + i);
            int iB = i + 512;
            bool vB = iB < nq;
            u64 e0 = ENC[pA.x & 524287u];
            u64 e1v = ENC[pA.y & 524287u];
            u64 e2 = ENC[pA.z & 524287u];
            u64 e3 = ENC[pA.w & 524287u];
            u64 e4, e5, e6, e7; unsigned d4, d5, d6, d7;
            if (vB) {
                uv4 pB = __builtin_nontemporal_load(pq + iB);
                e4 = ENC[pB.x & 524287u]; d4 = pB.x >> 19;
                e5 = ENC[pB.y & 524287u]; d5 = pB.y >> 19;
                e6 = ENC[pB.z & 524287u]; d6 = pB.z >> 19;
                e7 = ENC[pB.w & 524287u]; d7 = pB.w >> 19;
            }
            atomicAdd(&t[pA.x >> 19], e0);
            atomicAdd(&t[pA.y >> 19], e1v);
            atomicAdd(&t[pA.z >> 19], e2);
            atomicAdd(&t[pA.w >> 19], e3);
            if (vB) {
                atomicAdd(&t[d4], e4);
                atomicAdd(&t[d5], e5);
                atomicAdd(&t[d6], e6);
                atomicAdd(&t[d7], e7);
            }
        }
        int rem = n & 3;
        if ((int)threadIdx.x < rem) {
            unsigned p = pairs[lo + (nq << 2) + threadIdx.x];
            atomicAdd(&t[p >> 19], ENC[p & 524287u]);
        }
    }
    __syncthreads();
    u64* sb = slab + (size_t)blockIdx.x * BSZ;
    for (int j = threadIdx.x; j < BSZ; j += 512) sb[j] = t[j];
    __threadfence();
    __syncthreads();
    if (threadIdx.x == 0)
        lastS = (atomicAdd(&cnt2[B], 1) == M - 1) ? 1 : 0;
    __syncthreads();
    if (lastS) {
        int base = B << BSH;
        for (int j = threadIdx.x; j < BSZ; j += 512) {
            int node = base + j;
            if (node >= NN) continue;
            u64 s = 0ull;
#pragma unroll
            for (int m = 0; m < M; m++)
                s += __hip_atomic_load(&slab[(size_t)(B * M + m) * BSZ + j],
                                       __ATOMIC_RELAXED, __HIP_MEMORY_SCOPE_AGENT);
            unsigned sn = (unsigned)(s & 0x3FFFFFull);
            long long sv = (long long)(s - (u64)sn) >> 22;
            float su = (float)((double)sv * 1.4901161193847656e-08);   // 2^-26
            SU[node] = su;
            SN[node] = (float)sn;
        }
    }
}

// ---------------- agg pass 3: 4B gather from SU, f32 atomics -------------------
__global__ __launch_bounds__(512) void agg3k(
    const unsigned* __restrict__ pairs, const int* __restrict__ cur,
    const float* __restrict__ SU, float* __restrict__ slab)
{
    __shared__ float t[BSZ];   // 16 KB
    for (int j = threadIdx.x; j < BSZ; j += 512) t[j] = 0.f;
    __syncthreads();
    int B = blockIdx.x / M, sl = blockIdx.x % M;
    int b0 = B * CAP;
    int len = cur[B];
    int seg = (((len + M - 1) / M) + 3) & ~3;
    int lo = b0 + sl * seg;
    int hi = lo + seg, e1 = b0 + len;
    if (hi > e1) hi = e1;
    int n = hi - lo;
    if (n > 0) {
        int nq = n >> 2;
        const uv4* pq = (const uv4*)(pairs + lo);
        for (int i = threadIdx.x; i < nq; i += 1024) {
            uv4 pA = __builtin_nontemporal_load(pq + i);
            int iB = i + 512;
            bool vB = iB < nq;
            float a0 = SU[pA.x & 524287u];
            float a1 = SU[pA.y & 524287u];
            float a2 = SU[pA.z & 524287u];
            float a3 = SU[pA.w & 524287u];
            float c0, c1, c2, c3; unsigned d4, d5, d6, d7;
            if (vB) {
                uv4 pB = __builtin_nontemporal_load(pq + iB);
                c0 = SU[pB.x & 524287u]; d4 = pB.x >> 19;
                c1 = SU[pB.y & 524287u]; d5 = pB.y >> 19;
                c2 = SU[pB.z & 524287u]; d6 = pB.z >> 19;
                c3 = SU[pB.w & 524287u]; d7 = pB.w >> 19;
            }
            atomicAdd(&t[pA.x >> 19], a0);
            atomicAdd(&t[pA.y >> 19], a1);
            atomicAdd(&t[pA.z >> 19], a2);
            atomicAdd(&t[pA.w >> 19], a3);
            if (vB) {
                atomicAdd(&t[d4], c0);
                atomicAdd(&t[d5], c1);
                atomicAdd(&t[d6], c2);
                atomicAdd(&t[d7], c3);
            }
        }
        int rem = n & 3;
        if ((int)threadIdx.x < rem) {
            unsigned p = pairs[lo + (nq << 2) + threadIdx.x];
            atomicAdd(&t[p >> 19], SU[p & 524287u]);
        }
    }
    __syncthreads();
    float* sb = slab + (size_t)blockIdx.x * BSZ;
    for (int j = threadIdx.x; j < BSZ; j += 512)
        __builtin_nontemporal_store(t[j], sb + j);
}

// ---------------- fused: merge SSU + f64 moments of (u,n,su,sn,ssu) ------------
__global__ __launch_bounds__(256) void m3mom(
    const float* __restrict__ slab, const float2* __restrict__ UN2,
    const float* __restrict__ SU, const float* __restrict__ SN,
    float* __restrict__ SSU, double* __restrict__ dm)
{
    int i = blockIdx.x * 256 + threadIdx.x;
    double z[5] = {0, 0, 0, 0, 0};
    if (i < NN) {
        int B = i >> BSH, low = i & (BSZ - 1);
        float ssu = 0.f;
#pragma unroll
        for (int m = 0; m < M; m++)
            ssu += __builtin_nontemporal_load(slab + (size_t)(B * M + m) * BSZ + low);
        SSU[i] = ssu;
        float2 un = UN2[i];
        z[0] = (double)un.x; z[1] = (double)un.y; z[2] = (double)SU[i];
        z[3] = (double)SN[i]; z[4] = (double)ssu;
    }
    double m[20];
#pragma unroll
    for (int a = 0; a < 5; a++) m[a] = z[a];
    int idx = 5;
#pragma unroll
    for (int a = 0; a < 5; a++)
#pragma unroll
        for (int b = a; b < 5; b++) m[idx++] = z[a] * z[b];

    __shared__ double part[4][20];
    int lane = threadIdx.x & 63, wid = threadIdx.x >> 6;
#pragma unroll
    for (int k = 0; k < 20; k++) {
        double r = waveReduceD(m[k]);
        if (lane == 0) part[wid][k] = r;
    }
    __syncthreads();
    if (threadIdx.x < 20)
        atomicAdd(&dm[threadIdx.x],
                  part[0][threadIdx.x] + part[1][threadIdx.x] +
                  part[2][threadIdx.x] + part[3][threadIdx.x]);
}

// ---------------- K: fold weights + moments into the 4x6 logit matrix ----------
__device__ void mm1010(const float* in, const float* Wa, const float* Wb, float* out)
{
    float t[10];
    for (int m = 0; m < 10; m++) {
        float acc = 0.f;
        for (int k = 0; k < 10; k++) acc += in[k] * Wa[k * 10 + m];
        t[m] = acc;
    }
    for (int j = 0; j < 10; j++) {
        float acc = 0.f;
        for (int m = 0; m < 10; m++) acc += t[m] * Wb[m * 10 + j];
        out[j] = acc;
    }
}

__global__ void constk(
    const float* __restrict__ W1a, const float* __restrict__ b1a,
    const float* __restrict__ W1b, const float* __restrict__ b1b,
    const float* __restrict__ g1, const float* __restrict__ be1,
    const float* __restrict__ W2a, const float* __restrict__ b2a,
    const float* __restrict__ W2b, const float* __restrict__ b2b,
    const float* __restrict__ g2, const float* __restrict__ be2,
    const float* __restrict__ W3a, const float* __restrict__ b3a,
    const float* __restrict__ W3b, const float* __restrict__ b3b,
    const float* __restrict__ g3, const float* __restrict__ be3,
    const float* __restrict__ Wf, const float* __restrict__ bf_,
    const double* __restrict__ dm, float* __restrict__ Lout)
{
    if (threadIdx.x != 0 || blockIdx.x != 0) return;
    const double invN = 1.0 / (double)NN;
    double E[5];
    for (int m = 0; m < 5; m++) E[m] = dm[m] * invN;
    double C[5][5];
    {
        int idx = 5;
        for (int a = 0; a < 5; a++)
            for (int b = a; b < 5; b++) {
                double c = dm[idx++] * invN - E[a] * E[b];
                C[a][b] = c; C[b][a] = c;
            }
    }
    float v[10], c1[10];
    for (int j = 0; j < 10; j++) {
        float av = 0.f, ac = 0.f;
        for (int k = 0; k < 10; k++) {
            av += W1a[k] * W1b[k * 10 + j];
            ac += b1a[k] * W1b[k * 10 + j];
        }
        v[j] = av; c1[j] = ac + b1b[j];
    }
    double Eu = E[0], Vu = C[0][0];
    float p[10], q[10];
    for (int j = 0; j < 10; j++) {
        float var1 = (float)(Vu * (double)v[j] * (double)v[j]);
        float sc1 = g1[j] * rsqrtf(var1 + BN_EPS);
        p[j] = sc1 * v[j];
        q[j] = be1[j] - (float)Eu * p[j];
    }
    float r[10], s[10], d2[10];
    mm1010(p, W2a, W2b, r);
    mm1010(q, W2a, W2b, s);
    for (int j = 0; j < 10; j++) {
        float acc = b2b[j];
        for (int m = 0; m < 10; m++) acc += b2a[m] * W2b[m * 10 + j];
        d2[j] = acc;
    }
    double Ea = E[0] + E[2], Eb = 1.0 + E[1];
    double Va = C[0][0] + 2.0 * C[0][2] + C[2][2];
    double Vb = C[1][1];
    double Cab = C[0][1] + C[2][1];
    float rt[10], st[10], dt[10];
    for (int j = 0; j < 10; j++) {
        double rj = r[j], sj = s[j];
        float var2 = (float)(Va * rj * rj + Vb * sj * sj + 2.0 * Cab * rj * sj);
        float sc2 = g2[j] * rsqrtf(var2 + BN_EPS);
        rt[j] = sc2 * r[j];
        st[j] = sc2 * s[j];
        dt[j] = be2[j] - sc2 * (float)(Ea * rj + Eb * sj);
    }
    float r3[10], s3[10], t3[10], d3[10];
    mm1010(rt, W3a, W3b, r3);
    mm1010(st, W3a, W3b, s3);
    mm1010(dt, W3a, W3b, t3);
    for (int j = 0; j < 10; j++) {
        float acc = b3b[j];
        for (int m = 0; m < 10; m++) acc += b3a[m] * W3b[m * 10 + j];
        d3[j] = acc;
    }
    const double gA[5] = {1, 0, 2, 0, 1};
    const double gB[5] = {0, 2, 0, 1, 0};
    const double gC[5] = {0, 1, 0, 0, 0};
    double EA = E[0] + 2.0 * E[2] + E[4];
    double EB = 1.0 + 2.0 * E[1] + E[3];
    double EC = 1.0 + E[1];
    double VA = 0, VB = 0, VC = 0, CAB = 0, CAC = 0, CBC = 0;
    for (int a = 0; a < 5; a++)
        for (int b = 0; b < 5; b++) {
            double c = C[a][b];
            VA  += gA[a] * gA[b] * c;
            VB  += gB[a] * gB[b] * c;
            VC  += gC[a] * gC[b] * c;
            CAB += gA[a] * gB[b] * c;
            CAC += gA[a] * gC[b] * c;
            CBC += gB[a] * gC[b] * c;
        }
    float rh[10], sh[10], th[10], dh[10];
    for (int j = 0; j < 10; j++) {
        double rj = r3[j], sj = s3[j], tj = t3[j];
        float var3 = (float)(VA * rj * rj + VB * sj * sj + VC * tj * tj
                             + 2.0 * (CAB * rj * sj + CAC * rj * tj + CBC * sj * tj));
        float sc3 = g3[j] * rsqrtf(var3 + BN_EPS);
        rh[j] = sc3 * r3[j];
        sh[j] = sc3 * s3[j];
        th[j] = sc3 * t3[j];
        dh[j] = be3[j] - sc3 * (float)(EA * rj + EB * sj + EC * tj);
    }
    for (int k = 0; k < 4; k++) {
        float Lu = 0, Ln = 0, Lsu = 0, Lsn = 0, Lssu = 0, L0 = bf_[k];
        for (int j = 0; j < 10; j++) {
            float wf1 = Wf[j * 4 + k];
            float wf2 = Wf[(10 + j) * 4 + k];
            float wf3 = Wf[(20 + j) * 4 + k];
            Lu   += p[j] * wf1 + rt[j] * wf2 + rh[j] * wf3;
            Ln   += st[j] * wf2 + (2.f * sh[j] + th[j]) * wf3;
            Lsu  += rt[j] * wf2 + 2.f * rh[j] * wf3;
            Lsn  += sh[j] * wf3;
            Lssu += rh[j] * wf3;
            L0   += q[j] * wf1 + (st[j] + dt[j]) * wf2 + (sh[j] + th[j] + dh[j]) * wf3;
        }
        Lout[0 * 4 + k] = Lu;  Lout[1 * 4 + k] = Ln;   Lout[2 * 4 + k] = Lsu;
        Lout[3 * 4 + k] = Lsn; Lout[4 * 4 + k] = Lssu; Lout[5 * 4 + k] = L0;
    }
}

// ---------------- F: logits -> softmax -> s (f32 out + bf16 side table) --------
__global__ __launch_bounds__(256) void finalk(
    const float2* __restrict__ UN2, const float* __restrict__ SU,
    const float* __restrict__ SN, const float* __restrict__ SSU,
    const float* __restrict__ L,
    float4* __restrict__ sout, ushort4* __restrict__ sbf)
{
    __shared__ float sL[24];
    if (threadIdx.x < 24) sL[threadIdx.x] = L[threadIdx.x];
    __syncthreads();
    int i = blockIdx.x * 256 + threadIdx.x;
    if (i >= NN) return;
    float2 un = UN2[i];
    float u = un.x, n = un.y, su = SU[i], sn = SN[i], ssu = SSU[i];
    float lg[4];
#pragma unroll
    for (int k = 0; k < 4; k++)
        lg[k] = sL[k] * u + sL[4 + k] * n + sL[8 + k] * su
              + sL[12 + k] * sn + sL[16 + k] * ssu + sL[20 + k];
    float mx = fmaxf(fmaxf(lg[0], lg[1]), fmaxf(lg[2], lg[3]));
    float e0 = __expf(lg[0] - mx), e1 = __expf(lg[1] - mx);
    float e2 = __expf(lg[2] - mx), e3 = __expf(lg[3] - mx);
    float inv = 1.f / (e0 + e1 + e2 + e3);
    float s0 = e0 * inv, s1 = e1 * inv, s2 = e2 * inv, s3 = e3 * inv;
    fv4 o = {s0, s1, s2, s3};
    __builtin_nontemporal_store(o, (fv4*)sout + i);
    ushort4 pk; pk.x = f2u(s0); pk.y = f2u(s1); pk.z = f2u(s2); pk.w = f2u(s3);
    sbf[i] = pk;
}

// ---------------- modk: dst-side s in LDS, natural pipelining, fused q ---------
__device__ __forceinline__ void modacc(u64 ua, u64 ub, float we, float* acc) {
    float ax = u2f((unsigned short)ua),         ay = u2f((unsigned short)(ua >> 16));
    float az = u2f((unsigned short)(ua >> 32)), aw = u2f((unsigned short)(ua >> 48));
    float bx = u2f((unsigned short)ub),         by = u2f((unsigned short)(ub >> 16));
    float bz = u2f((unsigned short)(ub >> 32)), bw = u2f((unsigned short)(ub >> 48));
    acc[0] += we;
    acc[1] += we * (ax * bx + ay * by + az * bz + aw * bw);
    acc[2] += we * ax; acc[3] += we * ay;
    acc[4] += we * az; acc[5] += we * aw;
}

__global__ __launch_bounds__(512) void modkQ(
    const unsigned* __restrict__ pairs, const unsigned short* __restrict__ wp,
    const int* __restrict__ cur, const u64* __restrict__ sbfU,
    float* __restrict__ scal, int* __restrict__ cnt, float* __restrict__ outq)
{
    __shared__ u64 sS[BSZ];   // 32 KB: this bucket's dst-side s values
    int B = blockIdx.x / M, sl = blockIdx.x % M;
    for (int j = threadIdx.x; j < BSZ; j += 512) {
        int g = (B << BSH) + j;
        sS[j] = (g < NN) ? sbfU[g] : 0ull;
    }
    __syncthreads();
    int b0 = B * CAP;
    int len = cur[B];
    int seg = (((len + M - 1) / M) + 3) & ~3;
    int lo = b0 + sl * seg;
    int hi = lo + seg, e1 = b0 + len;
    if (hi > e1) hi = e1;
    int n = hi - lo;
    float acc[6] = {0, 0, 0, 0, 0, 0};
    if (n > 0) {
        int nq = n >> 2;
        const uv4* pq = (const uv4*)(pairs + lo);
        const u64* wq = (const u64*)(wp + lo);
        for (int i = threadIdx.x; i < nq; i += 1024) {
            uv4 pA = __builtin_nontemporal_load(pq + i);
            u64 wA = __builtin_nontemporal_load(wq + i);
            int iB = i + 512;
            bool vB = iB < nq;
            u64 a0 = sbfU[pA.x & 524287u];
            u64 a1 = sbfU[pA.y & 524287u];
            u64 a2 = sbfU[pA.z & 524287u];
            u64 a3 = sbfU[pA.w & 524287u];
            uv4 pB; u64 wB; u64 a4, a5, a6, a7;
            if (vB) {
                pB = __builtin_nontemporal_load(pq + iB);
                wB = __builtin_nontemporal_load(wq + iB);
                a4 = sbfU[pB.x & 524287u];
                a5 = sbfU[pB.y & 524287u];
                a6 = sbfU[pB.z & 524287u];
                a7 = sbfU[pB.w & 524287u];
            }
            modacc(a0, sS[pA.x >> 19], u2f((unsigned short)wA),         acc);
            modacc(a1, sS[pA.y >> 19], u2f((unsigned short)(wA >> 16)), acc);
            modacc(a2, sS[pA.z >> 19], u2f((unsigned short)(wA >> 32)), acc);
            modacc(a3, sS[pA.w >> 19], u2f((unsigned short)(wA >> 48)), acc);
            if (vB) {
                modacc(a4, sS[pB.x >> 19], u2f((unsigned short)wB),         acc);
                modacc(a5, sS[pB.y >> 19], u2f((unsigned short)(wB >> 16)), acc);
                modacc(a6, sS[pB.z >> 19], u2f((unsigned short)(wB >> 32)), acc);
                modacc(a7, sS[pB.w >> 19], u2f((unsigned short)(wB >> 48)), acc);
            }
        }
        int rem = n & 3;
        if ((int)threadIdx.x < rem) {
            int idx = lo + (nq << 2) + threadIdx.x;
            unsigned p = pairs[idx];
            modacc(sbfU[p & 524287u], sS[p >> 19], u2f(wp[idx]), acc);
        }
    }
    __shared__ float part[8][6];
    int lane = threadIdx.x & 63, wid = threadIdx.x >> 6;
#pragma unroll
    for (int k = 0; k < 6; k++) {
        float r = waveReduceF(acc[k]);
        if (lane == 0) part[wid][k] = r;
    }
    __syncthreads();
    if (threadIdx.x < 6) {
        float vsum = 0.f;
#pragma unroll
        for (int wdi = 0; wdi < 8; wdi++) vsum += part[wdi][threadIdx.x];
        int off = (threadIdx.x == 0) ? 128 : (threadIdx.x == 1 ? 129 : 130 + threadIdx.x);
        atomicAdd(&scal[off], vsum);
        __threadfence();
    }
    __syncthreads();
    if (threadIdx.x == 0) {
        if (atomicAdd(cnt, 1) == (int)gridDim.x - 1) {
            float tm = atomicAdd(&scal[128], 0.f);
            float pos = atomicAdd(&scal[129], 0.f);
            float inv = 1.f / tm;
            float posv = pos * inv;
            float acq = 0.f;
#pragma unroll
            for (int k = 0; k < 4; k++) {
                float d = atomicAdd(&scal[132 + k], 0.f) * inv;
                acq += d * d;
            }
            outq[(size_t)NN * 4] = posv - acq;
        }
    }
}

extern "C" void kernel_launch(void* const* d_in, const int* in_sizes, int n_in,
                              void* d_out, int out_size, void* d_ws, size_t ws_size,
                              hipStream_t stream) {
    const float* x  = (const float*)d_in[0];
    const int*  ei  = (const int*)d_in[1];
    const int*  src = ei;
    const int*  dst = ei + NE;
    const float* w   = (const float*)d_in[2];
    const float* W1a = (const float*)d_in[3];  const float* b1a = (const float*)d_in[4];
    const float* W1b = (const float*)d_in[5];  const float* b1b = (const float*)d_in[6];
    const float* g1  = (const float*)d_in[7];  const float* be1 = (const float*)d_in[8];
    const float* W2a = (const float*)d_in[9];  const float* b2a = (const float*)d_in[10];
    const float* W2b = (const float*)d_in[11]; const float* b2b = (const float*)d_in[12];
    const float* g2  = (const float*)d_in[13]; const float* be2 = (const float*)d_in[14];
    const float* W3a = (const float*)d_in[15]; const float* b3a = (const float*)d_in[16];
    const float* W3b = (const float*)d_in[17]; const float* b3b = (const float*)d_in[18];
    const float* g3  = (const float*)d_in[19]; const float* be3 = (const float*)d_in[20];
    const float* Wf  = (const float*)d_in[21]; const float* bfb = (const float*)d_in[22];

    // workspace layout:
    //  floats sc[0..1023]: two_m@128, pos@129, ds@132..135, L@160..183,
    //    dm (20 doubles) @ float-idx 384 (byte 1536),
    //    bucket counters r1 @ sci[448..570], r2 @ sci[576..698],
    //    cur ints @ sci[832..954], modk counter @ sci[961]  (all in 4KB memset)
    //  byte 4096: pairs uint[NB*CAP] (34.3MB) | wp ushort[NB*CAP] (17.1MB) |
    //    slab (32.25MB, u64[NAGG*BSZ] rounds 1/2, float[NAGG*BSZ] round 3) |
    //    UN2 float2[NN] | SU float[NN] | SN float[NN] | SSU float[NN] |
    //    sbf ushort4[NN] | ENC u64[NN]
    float*  sc   = (float*)d_ws;
    int*    sci  = (int*)d_ws;
    double* dm   = (double*)(sc + 384);
    unsigned* pairs = (unsigned*)(sc + 1024);
    unsigned short* wp = (unsigned short*)(pairs + (size_t)NB * CAP);
    float*  slab = (float*)(wp + (size_t)NB * CAP);
    u64*    slabU = (u64*)slab;
    float2* UN2  = (float2*)(slab + (size_t)NAGG * 2 * BSZ);
    float*  SU   = (float*)(UN2 + NN);
    float*  SN   = SU + NN;
    float*  SSU  = SN + NN;
    ushort4* sbf = (ushort4*)(SSU + NN);
    u64*    ENC  = (u64*)(sbf + NN);
    float*  sout = (float*)d_out;

    const int NB_N  = (NN + 255) / 256;
    const int NB_EQ = (NE / 4 + 1023) / 1024;   // 1954 blocks over int4-quads

    hipMemsetAsync(sc, 0, 4096, stream);

    // bucketize once (dst -> 123 fixed-capacity buckets), block counting sort
    scatterk<<<NB_EQ, 512, 0, stream>>>((const iv4*)src, (const iv4*)dst,
                                        (const fv4*)w, sci + 832, pairs, wp);

    // three aggregation rounds; merges fused into rounds 1/2 (last slice/bucket)
    agg1k<<<NAGG, 512, 0, stream>>>(pairs, sci + 832, x, slabU, sci + 448, UN2, ENC);
    agg2k<<<NAGG, 512, 0, stream>>>(pairs, sci + 832, ENC, slabU, sci + 576, SU, SN);
    agg3k<<<NAGG, 512, 0, stream>>>(pairs, sci + 832, SU, slab);
    m3mom<<<NB_N, 256, 0, stream>>>(slab, UN2, SU, SN, SSU, dm);

    // closed-form logit matrix (1 block, reg pressure isolated here)
    constk<<<1, 64, 0, stream>>>(W1a, b1a, W1b, b1b, g1, be1,
                                 W2a, b2a, W2b, b2b, g2, be2,
                                 W3a, b3a, W3b, b3b, g3, be3,
                                 Wf, bfb, dm, sc + 160);

    // softmax -> modularity (q fused into modk's last block)
    finalk<<<NB_N, 256, 0, stream>>>(UN2, SU, SN, SSU, sc + 160, (float4*)sout, sbf);
    modkQ<<<NAGG, 512, 0, stream>>>(pairs, wp, sci + 832, (const u64*)sbf, sc,
                                    sci + 961, sout);
}

// Round 6
// 536.145 us; speedup vs baseline: 2.0827x; 2.0827x over previous
//
#include <hip/hip_runtime.h>
#include <hip/hip_bf16.h>

#define NN 500000
#define NE 8000000
#define NB 123           // buckets of 4096 nodes: 123*4096 = 503808 >= NN
#define BSH 12
#define BSZ 4096
#define CAP 69632        // fixed bucket capacity (65536 mean + 16 sigma), mult of 4
#define M 8              // slices (blocks) per bucket
#define NAGG (NB * M)    // 984 blocks
#define BN_EPS 1e-5f

typedef unsigned uv4 __attribute__((ext_vector_type(4)));
typedef int iv4 __attribute__((ext_vector_type(4)));
typedef float fv4 __attribute__((ext_vector_type(4)));
typedef unsigned long long u64;

__device__ __forceinline__ float waveReduceF(float v) {
#pragma unroll
    for (int o = 32; o > 0; o >>= 1) v += __shfl_down(v, o, 64);
    return v;
}
__device__ __forceinline__ double waveReduceD(double v) {
#pragma unroll
    for (int o = 32; o > 0; o >>= 1) v += __shfl_down(v, o, 64);
    return v;
}
__device__ __forceinline__ float u2f(unsigned short u) {
    return __bfloat162float(__builtin_bit_cast(__hip_bfloat16, u));
}
__device__ __forceinline__ unsigned short f2u(float f) {
    return __builtin_bit_cast(unsigned short, __float2bfloat16(f));
}
// pack x-sample into (fixed<<20)+count1.  |x|<6 -> x*2^28 < 2^31 (int ok)
__device__ __forceinline__ u64 pk1(float v) {
    int iv = (int)rintf(v * 268435456.f);              // 2^28
    return ((u64)(long long)iv << 20) + 1ull;
}

// ---------------- bucketize: block counting sort, coalesced emit ---------------
__global__ __launch_bounds__(512) void scatterk(
    const iv4* __restrict__ src4, const iv4* __restrict__ dst4,
    const fv4* __restrict__ w4, int* __restrict__ cur,
    unsigned* __restrict__ pairs, unsigned short* __restrict__ wp)
{
    __shared__ unsigned sEnt[4096];        // 16 KB
    __shared__ unsigned short sW[4096];    // 8 KB
    __shared__ unsigned char sB[4096];     // 4 KB
    __shared__ int h[8][128];              // per-wave histograms
    __shared__ int wOff[8][128];           // cross-wave prefix per bucket
    __shared__ int bOff[128];              // block-local bucket prefix
    __shared__ int lb[128];                // global base for this block per bucket
    __shared__ int tot[128];

    int tid = threadIdx.x, wv = tid >> 6;
    for (int j = tid; j < 8 * 128; j += 512) (&h[0][0])[j] = 0;
    __syncthreads();

    unsigned en[8]; unsigned short wb[8]; int rb[8];   // rk<<8 | b, or -1
#pragma unroll
    for (int k = 0; k < 2; k++) {
        int q = blockIdx.x * 1024 + k * 512 + tid;
        if (q < NE / 4) {
            iv4 s4 = __builtin_nontemporal_load(src4 + q);
            iv4 d4 = __builtin_nontemporal_load(dst4 + q);
            fv4 ww = __builtin_nontemporal_load(w4 + q);
            int ss[4] = {s4.x, s4.y, s4.z, s4.w};
            int dd[4] = {d4.x, d4.y, d4.z, d4.w};
            float fw[4] = {ww.x, ww.y, ww.z, ww.w};
#pragma unroll
            for (int i = 0; i < 4; i++) {
                int d = dd[i], b = d >> BSH;
                en[k * 4 + i] = ((unsigned)(d & (BSZ - 1)) << 19) | (unsigned)ss[i];
                wb[k * 4 + i] = f2u(fw[i]);
                int rk = atomicAdd(&h[wv][b], 1);
                rb[k * 4 + i] = (rk << 8) | b;
            }
        } else {
#pragma unroll
            for (int i = 0; i < 4; i++) rb[k * 4 + i] = -1;
        }
    }
    __syncthreads();
    if (tid < NB) {
        int acc = 0;
#pragma unroll
        for (int w = 0; w < 8; w++) { wOff[w][tid] = acc; acc += h[w][tid]; }
        tot[tid] = acc;
        lb[tid] = tid * CAP + atomicAdd(&cur[tid], acc);
    }
    __syncthreads();
    // wave-parallel exclusive prefix of tot -> bOff (lanes 0..63, 2 elems each)
    if (tid < 64) {
        int lane = tid;
        int a = (2 * lane < NB) ? tot[2 * lane] : 0;
        int b = (2 * lane + 1 < NB) ? tot[2 * lane + 1] : 0;
        int s = a + b;
#pragma unroll
        for (int o = 1; o < 64; o <<= 1) {
            int t = __shfl_up(s, o, 64);
            if (lane >= o) s += t;
        }
        int excl = s - (a + b);
        bOff[2 * lane] = excl;
        bOff[2 * lane + 1] = excl + a;
    }
    __syncthreads();
#pragma unroll
    for (int k = 0; k < 8; k++) {
        if (rb[k] >= 0) {
            int b = rb[k] & 255, rk = rb[k] >> 8;
            int pos = bOff[b] + wOff[wv][b] + rk;
            sEnt[pos] = en[k]; sW[pos] = wb[k]; sB[pos] = (unsigned char)b;
        }
    }
    __syncthreads();
    int nE = NE - blockIdx.x * 4096; if (nE > 4096) nE = 4096;
    for (int j = tid; j < nE; j += 512) {
        int b = sB[j];
        int glob = lb[b] + (j - bOff[b]);
        __builtin_nontemporal_store(sEnt[j], pairs + glob);
        __builtin_nontemporal_store(sW[j], wp + glob);
    }
}

// ---------------- agg pass 1: packed u64 (x<<20 | count), natural pipelining ---
__global__ __launch_bounds__(512) void agg1k(
    const unsigned* __restrict__ pairs, const int* __restrict__ cur,
    const float* __restrict__ x, u64* __restrict__ slab)
{
    __shared__ u64 t[BSZ];   // 32 KB
    for (int j = threadIdx.x; j < BSZ; j += 512) t[j] = 0ull;
    __syncthreads();
    int B = blockIdx.x / M, sl = blockIdx.x % M;
    int b0 = B * CAP;
    int len = cur[B];
    int seg = (((len + M - 1) / M) + 3) & ~3;
    int lo = b0 + sl * seg;
    int hi = lo + seg, e1 = b0 + len;
    if (hi > e1) hi = e1;
    int n = hi - lo;
    if (n > 0) {
        int nq = n >> 2;
        const uv4* pq = (const uv4*)(pairs + lo);
        for (int i = threadIdx.x; i < nq; i += 1024) {
            uv4 pA = __builtin_nontemporal_load(pq + i);
            int iB = i + 512;
            bool vB = iB < nq;
            float a0 = x[pA.x & 524287u];
            float a1 = x[pA.y & 524287u];
            float a2 = x[pA.z & 524287u];
            float a3 = x[pA.w & 524287u];
            float c0, c1, c2, c3; unsigned d4, d5, d6, d7;
            if (vB) {
                uv4 pB = __builtin_nontemporal_load(pq + iB);
                c0 = x[pB.x & 524287u]; d4 = pB.x >> 19;
                c1 = x[pB.y & 524287u]; d5 = pB.y >> 19;
                c2 = x[pB.z & 524287u]; d6 = pB.z >> 19;
                c3 = x[pB.w & 524287u]; d7 = pB.w >> 19;
            }
            atomicAdd(&t[pA.x >> 19], pk1(a0));
            atomicAdd(&t[pA.y >> 19], pk1(a1));
            atomicAdd(&t[pA.z >> 19], pk1(a2));
            atomicAdd(&t[pA.w >> 19], pk1(a3));
            if (vB) {
                atomicAdd(&t[d4], pk1(c0));
                atomicAdd(&t[d5], pk1(c1));
                atomicAdd(&t[d6], pk1(c2));
                atomicAdd(&t[d7], pk1(c3));
            }
        }
        int rem = n & 3;
        if ((int)threadIdx.x < rem) {
            unsigned p = pairs[lo + (nq << 2) + threadIdx.x];
            atomicAdd(&t[p >> 19], pk1(x[p & 524287u]));
        }
    }
    __syncthreads();
    u64* sb = slab + (size_t)blockIdx.x * BSZ;
    for (int j = threadIdx.x; j < BSZ; j += 512)
        __builtin_nontemporal_store(t[j], sb + j);
}

// decode: count in low 20 bits, x-sum (2^-28 fixed) above.  Also emit the
// pre-packed agg2 operand ENC = (u*2^26)<<22 + n  (one 8B gather, one u64 atomic)
__global__ __launch_bounds__(256) void mergeN1(
    const u64* __restrict__ slab, const float* __restrict__ x,
    float2* __restrict__ UN2, u64* __restrict__ ENC)
{
    int i = blockIdx.x * 256 + threadIdx.x;
    if (i >= NN) return;
    int B = i >> BSH, low = i & (BSZ - 1);
    u64 s = 0ull;
#pragma unroll
    for (int m = 0; m < M; m++)
        s += __builtin_nontemporal_load(slab + (size_t)(B * M + m) * BSZ + low);
    unsigned cn = (unsigned)(s & 0xFFFFFull);
    long long sv = (long long)(s - (u64)cn) >> 20;
    float u = x[i] + (float)((double)sv * 3.725290298461914e-09);  // 2^-28
    UN2[i] = make_float2(u, (float)cn);
    long long iu = (long long)rintf(u * 67108864.f);               // 2^26
    ENC[i] = ((u64)iu << 22) + (u64)cn;
}

// ---------------- agg pass 2: gather pre-packed ENC, single u64 atomic ---------
__global__ __launch_bounds__(512) void agg2k(
    const unsigned* __restrict__ pairs, const int* __restrict__ cur,
    const u64* __restrict__ ENC, u64* __restrict__ slab)
{
    __shared__ u64 t[BSZ];   // 32 KB
    for (int j = threadIdx.x; j < BSZ; j += 512) t[j] = 0ull;
    __syncthreads();
    int B = blockIdx.x / M, sl = blockIdx.x % M;
    int b0 = B * CAP;
    int len = cur[B];
    int seg = (((len + M - 1) / M) + 3) & ~3;
    int lo = b0 + sl * seg;
    int hi = lo + seg, e1 = b0 + len;
    if (hi > e1) hi = e1;
    int n = hi - lo;
    if (n > 0) {
        int nq = n >> 2;
        const uv4* pq = (const uv4*)(pairs + lo);
        for (int i = threadIdx.x; i < nq; i += 1024) {
            uv4 pA = __builtin_nontemporal_load(pq + i);
            int iB = i + 512;
            bool vB = iB < nq;
            u64 e0 = ENC[pA.x & 524287u];
            u64 e1v = ENC[pA.y & 524287u];
            u64 e2 = ENC[pA.z & 524287u];
            u64 e3 = ENC[pA.w & 524287u];
            u64 e4, e5, e6, e7; unsigned d4, d5, d6, d7;
            if (vB) {
                uv4 pB = __builtin_nontemporal_load(pq + iB);
                e4 = ENC[pB.x & 524287u]; d4 = pB.x >> 19;
                e5 = ENC[pB.y & 524287u]; d5 = pB.y >> 19;
                e6 = ENC[pB.z & 524287u]; d6 = pB.z >> 19;
                e7 = ENC[pB.w & 524287u]; d7 = pB.w >> 19;
            }
            atomicAdd(&t[pA.x >> 19], e0);
            atomicAdd(&t[pA.y >> 19], e1v);
            atomicAdd(&t[pA.z >> 19], e2);
            atomicAdd(&t[pA.w >> 19], e3);
            if (vB) {
                atomicAdd(&t[d4], e4);
                atomicAdd(&t[d5], e5);
                atomicAdd(&t[d6], e6);
                atomicAdd(&t[d7], e7);
            }
        }
        int rem = n & 3;
        if ((int)threadIdx.x < rem) {
            unsigned p = pairs[lo + (nq << 2) + threadIdx.x];
            atomicAdd(&t[p >> 19], ENC[p & 524287u]);
        }
    }
    __syncthreads();
    u64* sb = slab + (size_t)blockIdx.x * BSZ;
    for (int j = threadIdx.x; j < BSZ; j += 512)
        __builtin_nontemporal_store(t[j], sb + j);
}

__global__ __launch_bounds__(256) void mergeN2(
    const u64* __restrict__ slab, float* __restrict__ SU, float* __restrict__ SN)
{
    int i = blockIdx.x * 256 + threadIdx.x;
    if (i >= NN) return;
    int B = i >> BSH, low = i & (BSZ - 1);
    u64 s = 0ull;
#pragma unroll
    for (int m = 0; m < M; m++)
        s += __builtin_nontemporal_load(slab + (size_t)(B * M + m) * BSZ + low);
    unsigned sn = (unsigned)(s & 0x3FFFFFull);
    long long sv = (long long)(s - (u64)sn) >> 22;
    float su = (float)((double)sv * 1.4901161193847656e-08);   // 2^-26
    SU[i] = su;
    SN[i] = (float)sn;
}

// ---------------- agg pass 3: 4B gather from SU, f32 atomics -------------------
__global__ __launch_bounds__(512) void agg3k(
    const unsigned* __restrict__ pairs, const int* __restrict__ cur,
    const float* __restrict__ SU, float* __restrict__ slab)
{
    __shared__ float t[BSZ];   // 16 KB
    for (int j = threadIdx.x; j < BSZ; j += 512) t[j] = 0.f;
    __syncthreads();
    int B = blockIdx.x / M, sl = blockIdx.x % M;
    int b0 = B * CAP;
    int len = cur[B];
    int seg = (((len + M - 1) / M) + 3) & ~3;
    int lo = b0 + sl * seg;
    int hi = lo + seg, e1 = b0 + len;
    if (hi > e1) hi = e1;
    int n = hi - lo;
    if (n > 0) {
        int nq = n >> 2;
        const uv4* pq = (const uv4*)(pairs + lo);
        for (int i = threadIdx.x; i < nq; i += 1024) {
            uv4 pA = __builtin_nontemporal_load(pq + i);
            int iB = i + 512;
            bool vB = iB < nq;
            float a0 = SU[pA.x & 524287u];
            float a1 = SU[pA.y & 524287u];
            float a2 = SU[pA.z & 524287u];
            float a3 = SU[pA.w & 524287u];
            float c0, c1, c2, c3; unsigned d4, d5, d6, d7;
            if (vB) {
                uv4 pB = __builtin_nontemporal_load(pq + iB);
                c0 = SU[pB.x & 524287u]; d4 = pB.x >> 19;
                c1 = SU[pB.y & 524287u]; d5 = pB.y >> 19;
                c2 = SU[pB.z & 524287u]; d6 = pB.z >> 19;
                c3 = SU[pB.w & 524287u]; d7 = pB.w >> 19;
            }
            atomicAdd(&t[pA.x >> 19], a0);
            atomicAdd(&t[pA.y >> 19], a1);
            atomicAdd(&t[pA.z >> 19], a2);
            atomicAdd(&t[pA.w >> 19], a3);
            if (vB) {
                atomicAdd(&t[d4], c0);
                atomicAdd(&t[d5], c1);
                atomicAdd(&t[d6], c2);
                atomicAdd(&t[d7], c3);
            }
        }
        int rem = n & 3;
        if ((int)threadIdx.x < rem) {
            unsigned p = pairs[lo + (nq << 2) + threadIdx.x];
            atomicAdd(&t[p >> 19], SU[p & 524287u]);
        }
    }
    __syncthreads();
    float* sb = slab + (size_t)blockIdx.x * BSZ;
    for (int j = threadIdx.x; j < BSZ; j += 512)
        __builtin_nontemporal_store(t[j], sb + j);
}

// ---------------- fused: merge SSU + f64 moments of (u,n,su,sn,ssu) ------------
__global__ __launch_bounds__(256) void m3mom(
    const float* __restrict__ slab, const float2* __restrict__ UN2,
    const float* __restrict__ SU, const float* __restrict__ SN,
    float* __restrict__ SSU, double* __restrict__ dm)
{
    int i = blockIdx.x * 256 + threadIdx.x;
    double z[5] = {0, 0, 0, 0, 0};
    if (i < NN) {
        int B = i >> BSH, low = i & (BSZ - 1);
        float ssu = 0.f;
#pragma unroll
        for (int m = 0; m < M; m++)
            ssu += __builtin_nontemporal_load(slab + (size_t)(B * M + m) * BSZ + low);
        SSU[i] = ssu;
        float2 un = UN2[i];
        z[0] = (double)un.x; z[1] = (double)un.y; z[2] = (double)SU[i];
        z[3] = (double)SN[i]; z[4] = (double)ssu;
    }
    double m[20];
#pragma unroll
    for (int a = 0; a < 5; a++) m[a] = z[a];
    int idx = 5;
#pragma unroll
    for (int a = 0; a < 5; a++)
#pragma unroll
        for (int b = a; b < 5; b++) m[idx++] = z[a] * z[b];

    __shared__ double part[4][20];
    int lane = threadIdx.x & 63, wid = threadIdx.x >> 6;
#pragma unroll
    for (int k = 0; k < 20; k++) {
        double r = waveReduceD(m[k]);
        if (lane == 0) part[wid][k] = r;
    }
    __syncthreads();
    if (threadIdx.x < 20)
        atomicAdd(&dm[threadIdx.x],
                  part[0][threadIdx.x] + part[1][threadIdx.x] +
                  part[2][threadIdx.x] + part[3][threadIdx.x]);
}

// ---------------- K: fold weights + moments into the 4x6 logit matrix ----------
__device__ void mm1010(const float* in, const float* Wa, const float* Wb, float* out)
{
    float t[10];
    for (int m = 0; m < 10; m++) {
        float acc = 0.f;
        for (int k = 0; k < 10; k++) acc += in[k] * Wa[k * 10 + m];
        t[m] = acc;
    }
    for (int j = 0; j < 10; j++) {
        float acc = 0.f;
        for (int m = 0; m < 10; m++) acc += t[m] * Wb[m * 10 + j];
        out[j] = acc;
    }
}

__global__ void constk(
    const float* __restrict__ W1a, const float* __restrict__ b1a,
    const float* __restrict__ W1b, const float* __restrict__ b1b,
    const float* __restrict__ g1, const float* __restrict__ be1,
    const float* __restrict__ W2a, const float* __restrict__ b2a,
    const float* __restrict__ W2b, const float* __restrict__ b2b,
    const float* __restrict__ g2, const float* __restrict__ be2,
    const float* __restrict__ W3a, const float* __restrict__ b3a,
    const float* __restrict__ W3b, const float* __restrict__ b3b,
    const float* __restrict__ g3, const float* __restrict__ be3,
    const float* __restrict__ Wf, const float* __restrict__ bf_,
    const double* __restrict__ dm, float* __restrict__ Lout)
{
    if (threadIdx.x != 0 || blockIdx.x != 0) return;
    const double invN = 1.0 / (double)NN;
    double E[5];
    for (int m = 0; m < 5; m++) E[m] = dm[m] * invN;
    double C[5][5];
    {
        int idx = 5;
        for (int a = 0; a < 5; a++)
            for (int b = a; b < 5; b++) {
                double c = dm[idx++] * invN - E[a] * E[b];
                C[a][b] = c; C[b][a] = c;
            }
    }
    float v[10], c1[10];
    for (int j = 0; j < 10; j++) {
        float av = 0.f, ac = 0.f;
        for (int k = 0; k < 10; k++) {
            av += W1a[k] * W1b[k * 10 + j];
            ac += b1a[k] * W1b[k * 10 + j];
        }
        v[j] = av; c1[j] = ac + b1b[j];
    }
    double Eu = E[0], Vu = C[0][0];
    float p[10], q[10];
    for (int j = 0; j < 10; j++) {
        float var1 = (float)(Vu * (double)v[j] * (double)v[j]);
        float sc1 = g1[j] * rsqrtf(var1 + BN_EPS);
        p[j] = sc1 * v[j];
        q[j] = be1[j] - (float)Eu * p[j];
    }
    float r[10], s[10], d2[10];
    mm1010(p, W2a, W2b, r);
    mm1010(q, W2a, W2b, s);
    for (int j = 0; j < 10; j++) {
        float acc = b2b[j];
        for (int m = 0; m < 10; m++) acc += b2a[m] * W2b[m * 10 + j];
        d2[j] = acc;
    }
    double Ea = E[0] + E[2], Eb = 1.0 + E[1];
    double Va = C[0][0] + 2.0 * C[0][2] + C[2][2];
    double Vb = C[1][1];
    double Cab = C[0][1] + C[2][1];
    float rt[10], st[10], dt[10];
    for (int j = 0; j < 10; j++) {
        double rj = r[j], sj = s[j];
        float var2 = (float)(Va * rj * rj + Vb * sj * sj + 2.0 * Cab * rj * sj);
        float sc2 = g2[j] * rsqrtf(var2 + BN_EPS);
        rt[j] = sc2 * r[j];
        st[j] = sc2 * s[j];
        dt[j] = be2[j] - sc2 * (float)(Ea * rj + Eb * sj);
    }
    float r3[10], s3[10], t3[10], d3[10];
    mm1010(rt, W3a, W3b, r3);
    mm1010(st, W3a, W3b, s3);
    mm1010(dt, W3a, W3b, t3);
    for (int j = 0; j < 10; j++) {
        float acc = b3b[j];
        for (int m = 0; m < 10; m++) acc += b3a[m] * W3b[m * 10 + j];
        d3[j] = acc;
    }
    const double gA[5] = {1, 0, 2, 0, 1};
    const double gB[5] = {0, 2, 0, 1, 0};
    const double gC[5] = {0, 1, 0, 0, 0};
    double EA = E[0] + 2.0 * E[2] + E[4];
    double EB = 1.0 + 2.0 * E[1] + E[3];
    double EC = 1.0 + E[1];
    double VA = 0, VB = 0, VC = 0, CAB = 0, CAC = 0, CBC = 0;
    for (int a = 0; a < 5; a++)
        for (int b = 0; b < 5; b++) {
            double c = C[a][b];
            VA  += gA[a] * gA[b] * c;
            VB  += gB[a] * gB[b] * c;
            VC  += gC[a] * gC[b] * c;
            CAB += gA[a] * gB[b] * c;
            CAC += gA[a] * gC[b] * c;
            CBC += gB[a] * gC[b] * c;
        }
    float rh[10], sh[10], th[10], dh[10];
    for (int j = 0; j < 10; j++) {
        double rj = r3[j], sj = s3[j], tj = t3[j];
        float var3 = (float)(VA * rj * rj + VB * sj * sj + VC * tj * tj
                             + 2.0 * (CAB * rj * sj + CAC * rj * tj + CBC * sj * tj));
        float sc3 = g3[j] * rsqrtf(var3 + BN_EPS);
        rh[j] = sc3 * r3[j];
        sh[j] = sc3 * s3[j];
        th[j] = sc3 * t3[j];
        dh[j] = be3[j] - sc3 * (float)(EA * rj + EB * sj + EC * tj);
    }
    for (int k = 0; k < 4; k++) {
        float Lu = 0, Ln = 0, Lsu = 0, Lsn = 0, Lssu = 0, L0 = bf_[k];
        for (int j = 0; j < 10; j++) {
            float wf1 = Wf[j * 4 + k];
            float wf2 = Wf[(10 + j) * 4 + k];
            float wf3 = Wf[(20 + j) * 4 + k];
            Lu   += p[j] * wf1 + rt[j] * wf2 + rh[j] * wf3;
            Ln   += st[j] * wf2 + (2.f * sh[j] + th[j]) * wf3;
            Lsu  += rt[j] * wf2 + 2.f * rh[j] * wf3;
            Lsn  += sh[j] * wf3;
            Lssu += rh[j] * wf3;
            L0   += q[j] * wf1 + (st[j] + dt[j]) * wf2 + (sh[j] + th[j] + dh[j]) * wf3;
        }
        Lout[0 * 4 + k] = Lu;  Lout[1 * 4 + k] = Ln;   Lout[2 * 4 + k] = Lsu;
        Lout[3 * 4 + k] = Lsn; Lout[4 * 4 + k] = Lssu; Lout[5 * 4 + k] = L0;
    }
}

// ---------------- F: logits -> softmax -> s (f32 out + bf16 side table) --------
__global__ __launch_bounds__(256) void finalk(
    const float2* __restrict__ UN2, const float* __restrict__ SU,
    const float* __restrict__ SN, const float* __restrict__ SSU,
    const float* __restrict__ L,
    float4* __restrict__ sout, ushort4* __restrict__ sbf)
{
    __shared__ float sL[24];
    if (threadIdx.x < 24) sL[threadIdx.x] = L[threadIdx.x];
    __syncthreads();
    int i = blockIdx.x * 256 + threadIdx.x;
    if (i >= NN) return;
    float2 un = UN2[i];
    float u = un.x, n = un.y, su = SU[i], sn = SN[i], ssu = SSU[i];
    float lg[4];
#pragma unroll
    for (int k = 0; k < 4; k++)
        lg[k] = sL[k] * u + sL[4 + k] * n + sL[8 + k] * su
              + sL[12 + k] * sn + sL[16 + k] * ssu + sL[20 + k];
    float mx = fmaxf(fmaxf(lg[0], lg[1]), fmaxf(lg[2], lg[3]));
    float e0 = __expf(lg[0] - mx), e1 = __expf(lg[1] - mx);
    float e2 = __expf(lg[2] - mx), e3 = __expf(lg[3] - mx);
    float inv = 1.f / (e0 + e1 + e2 + e3);
    float s0 = e0 * inv, s1 = e1 * inv, s2 = e2 * inv, s3 = e3 * inv;
    fv4 o = {s0, s1, s2, s3};
    __builtin_nontemporal_store(o, (fv4*)sout + i);
    ushort4 pk; pk.x = f2u(s0); pk.y = f2u(s1); pk.z = f2u(s2); pk.w = f2u(s3);
    sbf[i] = pk;
}

// ---------------- modk: dst-side s in LDS, natural pipelining, fused q ---------
__device__ __forceinline__ void modacc(u64 ua, u64 ub, float we, float* acc) {
    float ax = u2f((unsigned short)ua),         ay = u2f((unsigned short)(ua >> 16));
    float az = u2f((unsigned short)(ua >> 32)), aw = u2f((unsigned short)(ua >> 48));
    float bx = u2f((unsigned short)ub),         by = u2f((unsigned short)(ub >> 16));
    float bz = u2f((unsigned short)(ub >> 32)), bw = u2f((unsigned short)(ub >> 48));
    acc[0] += we;
    acc[1] += we * (ax * bx + ay * by + az * bz + aw * bw);
    acc[2] += we * ax; acc[3] += we * ay;
    acc[4] += we * az; acc[5] += we * aw;
}

__global__ __launch_bounds__(512) void modkQ(
    const unsigned* __restrict__ pairs, const unsigned short* __restrict__ wp,
    const int* __restrict__ cur, const u64* __restrict__ sbfU,
    float* __restrict__ scal, int* __restrict__ cnt, float* __restrict__ outq)
{
    __shared__ u64 sS[BSZ];   // 32 KB: this bucket's dst-side s values
    int B = blockIdx.x / M, sl = blockIdx.x % M;
    for (int j = threadIdx.x; j < BSZ; j += 512) {
        int g = (B << BSH) + j;
        sS[j] = (g < NN) ? sbfU[g] : 0ull;
    }
    __syncthreads();
    int b0 = B * CAP;
    int len = cur[B];
    int seg = (((len + M - 1) / M) + 3) & ~3;
    int lo = b0 + sl * seg;
    int hi = lo + seg, e1 = b0 + len;
    if (hi > e1) hi = e1;
    int n = hi - lo;
    float acc[6] = {0, 0, 0, 0, 0, 0};
    if (n > 0) {
        int nq = n >> 2;
        const uv4* pq = (const uv4*)(pairs + lo);
        const u64* wq = (const u64*)(wp + lo);
        for (int i = threadIdx.x; i < nq; i += 1024) {
            uv4 pA = __builtin_nontemporal_load(pq + i);
            u64 wA = __builtin_nontemporal_load(wq + i);
            int iB = i + 512;
            bool vB = iB < nq;
            u64 a0 = sbfU[pA.x & 524287u];
            u64 a1 = sbfU[pA.y & 524287u];
            u64 a2 = sbfU[pA.z & 524287u];
            u64 a3 = sbfU[pA.w & 524287u];
            uv4 pB; u64 wB; u64 a4, a5, a6, a7;
            if (vB) {
                pB = __builtin_nontemporal_load(pq + iB);
                wB = __builtin_nontemporal_load(wq + iB);
                a4 = sbfU[pB.x & 524287u];
                a5 = sbfU[pB.y & 524287u];
                a6 = sbfU[pB.z & 524287u];
                a7 = sbfU[pB.w & 524287u];
            }
            modacc(a0, sS[pA.x >> 19], u2f((unsigned short)wA),         acc);
            modacc(a1, sS[pA.y >> 19], u2f((unsigned short)(wA >> 16)), acc);
            modacc(a2, sS[pA.z >> 19], u2f((unsigned short)(wA >> 32)), acc);
            modacc(a3, sS[pA.w >> 19], u2f((unsigned short)(wA >> 48)), acc);
            if (vB) {
                modacc(a4, sS[pB.x >> 19], u2f((unsigned short)wB),         acc);
                modacc(a5, sS[pB.y >> 19], u2f((unsigned short)(wB >> 16)), acc);
                modacc(a6, sS[pB.z >> 19], u2f((unsigned short)(wB >> 32)), acc);
                modacc(a7, sS[pB.w >> 19], u2f((unsigned short)(wB >> 48)), acc);
            }
        }
        int rem = n & 3;
        if ((int)threadIdx.x < rem) {
            int idx = lo + (nq << 2) + threadIdx.x;
            unsigned p = pairs[idx];
            modacc(sbfU[p & 524287u], sS[p >> 19], u2f(wp[idx]), acc);
        }
    }
    __shared__ float part[8][6];
    int lane = threadIdx.x & 63, wid = threadIdx.x >> 6;
#pragma unroll
    for (int k = 0; k < 6; k++) {
        float r = waveReduceF(acc[k]);
        if (lane == 0) part[wid][k] = r;
    }
    __syncthreads();
    if (threadIdx.x < 6) {
        float vsum = 0.f;
#pragma unroll
        for (int wdi = 0; wdi < 8; wdi++) vsum += part[wdi][threadIdx.x];
        int off = (threadIdx.x == 0) ? 128 : (threadIdx.x == 1 ? 129 : 130 + threadIdx.x);
        atomicAdd(&scal[off], vsum);
        __threadfence();
    }
    __syncthreads();
    if (threadIdx.x == 0) {
        if (atomicAdd(cnt, 1) == (int)gridDim.x - 1) {
            float tm = atomicAdd(&scal[128], 0.f);
            float pos = atomicAdd(&scal[129], 0.f);
            float inv = 1.f / tm;
            float posv = pos * inv;
            float acq = 0.f;
#pragma unroll
            for (int k = 0; k < 4; k++) {
                float d = atomicAdd(&scal[132 + k], 0.f) * inv;
                acq += d * d;
            }
            outq[(size_t)NN * 4] = posv - acq;
        }
    }
}

extern "C" void kernel_launch(void* const* d_in, const int* in_sizes, int n_in,
                              void* d_out, int out_size, void* d_ws, size_t ws_size,
                              hipStream_t stream) {
    const float* x  = (const float*)d_in[0];
    const int*  ei  = (const int*)d_in[1];
    const int*  src = ei;
    const int*  dst = ei + NE;
    const float* w   = (const float*)d_in[2];
    const float* W1a = (const float*)d_in[3];  const float* b1a = (const float*)d_in[4];
    const float* W1b = (const float*)d_in[5];  const float* b1b = (const float*)d_in[6];
    const float* g1  = (const float*)d_in[7];  const float* be1 = (const float*)d_in[8];
    const float* W2a = (const float*)d_in[9];  const float* b2a = (const float*)d_in[10];
    const float* W2b = (const float*)d_in[11]; const float* b2b = (const float*)d_in[12];
    const float* g2  = (const float*)d_in[13]; const float* be2 = (const float*)d_in[14];
    const float* W3a = (const float*)d_in[15]; const float* b3a = (const float*)d_in[16];
    const float* W3b = (const float*)d_in[17]; const float* b3b = (const float*)d_in[18];
    const float* g3  = (const float*)d_in[19]; const float* be3 = (const float*)d_in[20];
    const float* Wf  = (const float*)d_in[21]; const float* bfb = (const float*)d_in[22];

    // workspace layout:
    //  floats sc[0..1023]: two_m@128, pos@129, ds@132..135, L@160..183,
    //    dm (20 doubles) @ float-idx 384 (byte 1536),
    //    cur ints @ sci[832..954], modk counter @ sci[961]  (all in 4KB memset)
    //  byte 4096: pairs uint[NB*CAP] (34.3MB) | wp ushort[NB*CAP] (17.1MB) |
    //    slab (32.25MB, u64[NAGG*BSZ] rounds 1/2, float[NAGG*BSZ] round 3) |
    //    UN2 float2[NN] | SU float[NN] | SN float[NN] | SSU float[NN] |
    //    sbf ushort4[NN] | ENC u64[NN]
    float*  sc   = (float*)d_ws;
    int*    sci  = (int*)d_ws;
    double* dm   = (double*)(sc + 384);
    unsigned* pairs = (unsigned*)(sc + 1024);
    unsigned short* wp = (unsigned short*)(pairs + (size_t)NB * CAP);
    float*  slab = (float*)(wp + (size_t)NB * CAP);
    u64*    slabU = (u64*)slab;
    float2* UN2  = (float2*)(slab + (size_t)NAGG * 2 * BSZ);
    float*  SU   = (float*)(UN2 + NN);
    float*  SN   = SU + NN;
    float*  SSU  = SN + NN;
    ushort4* sbf = (ushort4*)(SSU + NN);
    u64*    ENC  = (u64*)(sbf + NN);
    float*  sout = (float*)d_out;

    const int NB_N  = (NN + 255) / 256;
    const int NB_EQ = (NE / 4 + 1023) / 1024;   // 1954 blocks over int4-quads

    hipMemsetAsync(sc, 0, 4096, stream);

    // bucketize once (dst -> 123 fixed-capacity buckets), block counting sort
    scatterk<<<NB_EQ, 512, 0, stream>>>((const iv4*)src, (const iv4*)dst,
                                        (const fv4*)w, sci + 832, pairs, wp);

    // three aggregation rounds; packed u64 atomics in rounds 1/2
    agg1k<<<NAGG, 512, 0, stream>>>(pairs, sci + 832, x, slabU);
    mergeN1<<<NB_N, 256, 0, stream>>>(slabU, x, UN2, ENC);
    agg2k<<<NAGG, 512, 0, stream>>>(pairs, sci + 832, ENC, slabU);
    mergeN2<<<NB_N, 256, 0, stream>>>(slabU, SU, SN);
    agg3k<<<NAGG, 512, 0, stream>>>(pairs, sci + 832, SU, slab);
    m3mom<<<NB_N, 256, 0, stream>>>(slab, UN2, SU, SN, SSU, dm);

    // closed-form logit matrix (1 block, reg pressure isolated here)
    constk<<<1, 64, 0, stream>>>(W1a, b1a, W1b, b1b, g1, be1,
                                 W2a, b2a, W2b, b2b, g2, be2,
                                 W3a, b3a, W3b, b3b, g3, be3,
                                 Wf, bfb, dm, sc + 160);

    // softmax -> modularity (q fused into modk's last block)
    finalk<<<NB_N, 256, 0, stream>>>(UN2, SU, SN, SSU, sc + 160, (float4*)sout, sbf);
    modkQ<<<NAGG, 512, 0, stream>>>(pairs, wp, sci + 832, (const u64*)sbf, sc,
                                    sci + 961, sout);
}

// Round 7
// 505.691 us; speedup vs baseline: 2.2081x; 1.0602x over previous
//
#include <hip/hip_runtime.h>
#include <hip/hip_bf16.h>

#define NN 500000
#define NE 8000000
#define NB 123           // buckets of 4096 nodes: 123*4096 = 503808 >= NN
#define BSH 12
#define BSZ 4096
#define CAP 69632        // fixed bucket capacity (65536 mean + 16 sigma), mult of 4
#define M 8              // slices (blocks) per bucket
#define NAGG (NB * M)    // 984 blocks
#define BN_EPS 1e-5f

typedef unsigned uv4 __attribute__((ext_vector_type(4)));
typedef int iv4 __attribute__((ext_vector_type(4)));
typedef float fv4 __attribute__((ext_vector_type(4)));
typedef unsigned long long u64;

__device__ __forceinline__ float waveReduceF(float v) {
#pragma unroll
    for (int o = 32; o > 0; o >>= 1) v += __shfl_down(v, o, 64);
    return v;
}
__device__ __forceinline__ double waveReduceD(double v) {
#pragma unroll
    for (int o = 32; o > 0; o >>= 1) v += __shfl_down(v, o, 64);
    return v;
}
__device__ __forceinline__ float u2f(unsigned short u) {
    return __bfloat162float(__builtin_bit_cast(__hip_bfloat16, u));
}
__device__ __forceinline__ unsigned short f2u(float f) {
    return __builtin_bit_cast(unsigned short, __float2bfloat16(f));
}
// pack x-sample into (fixed<<20)+count1.  |x|<6 -> x*2^28 < 2^31 (int ok)
__device__ __forceinline__ u64 pk1(float v) {
    int iv = (int)rintf(v * 268435456.f);              // 2^28
    return ((u64)(long long)iv << 20) + 1ull;
}

// ---------------- bucketize: block counting sort, coalesced emit ---------------
__global__ __launch_bounds__(512) void scatterk(
    const iv4* __restrict__ src4, const iv4* __restrict__ dst4,
    const fv4* __restrict__ w4, int* __restrict__ cur,
    unsigned* __restrict__ pairs, unsigned short* __restrict__ wp)
{
    __shared__ unsigned sEnt[4096];        // 16 KB
    __shared__ unsigned short sW[4096];    // 8 KB
    __shared__ unsigned char sB[4096];     // 4 KB
    __shared__ int h[8][128];              // per-wave histograms
    __shared__ int wOff[8][128];           // cross-wave prefix per bucket
    __shared__ int bOff[128];              // block-local bucket prefix
    __shared__ int lb[128];                // global base for this block per bucket
    __shared__ int tot[128];

    int tid = threadIdx.x, wv = tid >> 6;
    for (int j = tid; j < 8 * 128; j += 512) (&h[0][0])[j] = 0;
    __syncthreads();

    unsigned en[8]; unsigned short wb[8]; int rb[8];   // rk<<8 | b, or -1
#pragma unroll
    for (int k = 0; k < 2; k++) {
        int q = blockIdx.x * 1024 + k * 512 + tid;
        if (q < NE / 4) {
            iv4 s4 = __builtin_nontemporal_load(src4 + q);
            iv4 d4 = __builtin_nontemporal_load(dst4 + q);
            fv4 ww = __builtin_nontemporal_load(w4 + q);
            int ss[4] = {s4.x, s4.y, s4.z, s4.w};
            int dd[4] = {d4.x, d4.y, d4.z, d4.w};
            float fw[4] = {ww.x, ww.y, ww.z, ww.w};
#pragma unroll
            for (int i = 0; i < 4; i++) {
                int d = dd[i], b = d >> BSH;
                en[k * 4 + i] = ((unsigned)(d & (BSZ - 1)) << 19) | (unsigned)ss[i];
                wb[k * 4 + i] = f2u(fw[i]);
                int rk = atomicAdd(&h[wv][b], 1);
                rb[k * 4 + i] = (rk << 8) | b;
            }
        } else {
#pragma unroll
            for (int i = 0; i < 4; i++) rb[k * 4 + i] = -1;
        }
    }
    __syncthreads();
    if (tid < NB) {
        int acc = 0;
#pragma unroll
        for (int w = 0; w < 8; w++) { wOff[w][tid] = acc; acc += h[w][tid]; }
        tot[tid] = acc;
        lb[tid] = tid * CAP + atomicAdd(&cur[tid], acc);
    }
    __syncthreads();
    // wave-parallel exclusive prefix of tot -> bOff (lanes 0..63, 2 elems each)
    if (tid < 64) {
        int lane = tid;
        int a = (2 * lane < NB) ? tot[2 * lane] : 0;
        int b = (2 * lane + 1 < NB) ? tot[2 * lane + 1] : 0;
        int s = a + b;
#pragma unroll
        for (int o = 1; o < 64; o <<= 1) {
            int t = __shfl_up(s, o, 64);
            if (lane >= o) s += t;
        }
        int excl = s - (a + b);
        bOff[2 * lane] = excl;
        bOff[2 * lane + 1] = excl + a;
    }
    __syncthreads();
#pragma unroll
    for (int k = 0; k < 8; k++) {
        if (rb[k] >= 0) {
            int b = rb[k] & 255, rk = rb[k] >> 8;
            int pos = bOff[b] + wOff[wv][b] + rk;
            sEnt[pos] = en[k]; sW[pos] = wb[k]; sB[pos] = (unsigned char)b;
        }
    }
    __syncthreads();
    int nE = NE - blockIdx.x * 4096; if (nE > 4096) nE = 4096;
    for (int j = tid; j < nE; j += 512) {
        int b = sB[j];
        int glob = lb[b] + (j - bOff[b]);
        __builtin_nontemporal_store(sEnt[j], pairs + glob);
        __builtin_nontemporal_store(sW[j], wp + glob);
    }
}

// ---------------- agg pass 1: packed u64 (x<<20 | count), natural pipelining ---
__global__ __launch_bounds__(512) void agg1k(
    const unsigned* __restrict__ pairs, const int* __restrict__ cur,
    const float* __restrict__ x, u64* __restrict__ slab)
{
    __shared__ u64 t[BSZ];   // 32 KB
    for (int j = threadIdx.x; j < BSZ; j += 512) t[j] = 0ull;
    __syncthreads();
    int B = blockIdx.x / M, sl = blockIdx.x % M;
    int b0 = B * CAP;
    int len = cur[B];
    int seg = (((len + M - 1) / M) + 3) & ~3;
    int lo = b0 + sl * seg;
    int hi = lo + seg, e1 = b0 + len;
    if (hi > e1) hi = e1;
    int n = hi - lo;
    if (n > 0) {
        int nq = n >> 2;
        const uv4* pq = (const uv4*)(pairs + lo);
        for (int i = threadIdx.x; i < nq; i += 1024) {
            uv4 pA = __builtin_nontemporal_load(pq + i);
            int iB = i + 512;
            bool vB = iB < nq;
            float a0 = x[pA.x & 524287u];
            float a1 = x[pA.y & 524287u];
            float a2 = x[pA.z & 524287u];
            float a3 = x[pA.w & 524287u];
            float c0, c1, c2, c3; unsigned d4, d5, d6, d7;
            if (vB) {
                uv4 pB = __builtin_nontemporal_load(pq + iB);
                c0 = x[pB.x & 524287u]; d4 = pB.x >> 19;
                c1 = x[pB.y & 524287u]; d5 = pB.y >> 19;
                c2 = x[pB.z & 524287u]; d6 = pB.z >> 19;
                c3 = x[pB.w & 524287u]; d7 = pB.w >> 19;
            }
            atomicAdd(&t[pA.x >> 19], pk1(a0));
            atomicAdd(&t[pA.y >> 19], pk1(a1));
            atomicAdd(&t[pA.z >> 19], pk1(a2));
            atomicAdd(&t[pA.w >> 19], pk1(a3));
            if (vB) {
                atomicAdd(&t[d4], pk1(c0));
                atomicAdd(&t[d5], pk1(c1));
                atomicAdd(&t[d6], pk1(c2));
                atomicAdd(&t[d7], pk1(c3));
            }
        }
        int rem = n & 3;
        if ((int)threadIdx.x < rem) {
            unsigned p = pairs[lo + (nq << 2) + threadIdx.x];
            atomicAdd(&t[p >> 19], pk1(x[p & 524287u]));
        }
    }
    __syncthreads();
    u64* sb = slab + (size_t)blockIdx.x * BSZ;
    for (int j = threadIdx.x; j < BSZ; j += 512)
        __builtin_nontemporal_store(t[j], sb + j);
}

// decode: count in low 20 bits, x-sum (2^-28 fixed) above.  Also emit the
// pre-packed agg2 operand ENC = (u*2^26)<<22 + n  (one 8B gather, one u64 atomic)
__global__ __launch_bounds__(256) void mergeN1(
    const u64* __restrict__ slab, const float* __restrict__ x,
    float2* __restrict__ UN2, u64* __restrict__ ENC)
{
    int i = blockIdx.x * 256 + threadIdx.x;
    if (i >= NN) return;
    int B = i >> BSH, low = i & (BSZ - 1);
    u64 s = 0ull;
#pragma unroll
    for (int m = 0; m < M; m++)
        s += __builtin_nontemporal_load(slab + (size_t)(B * M + m) * BSZ + low);
    unsigned cn = (unsigned)(s & 0xFFFFFull);
    long long sv = (long long)(s - (u64)cn) >> 20;
    float u = x[i] + (float)((double)sv * 3.725290298461914e-09);  // 2^-28
    UN2[i] = make_float2(u, (float)cn);
    long long iu = (long long)rintf(u * 67108864.f);               // 2^26
    ENC[i] = ((u64)iu << 22) + (u64)cn;
}

// ---------------- agg pass 2: gather pre-packed ENC, single u64 atomic ---------
__global__ __launch_bounds__(512) void agg2k(
    const unsigned* __restrict__ pairs, const int* __restrict__ cur,
    const u64* __restrict__ ENC, u64* __restrict__ slab)
{
    __shared__ u64 t[BSZ];   // 32 KB
    for (int j = threadIdx.x; j < BSZ; j += 512) t[j] = 0ull;
    __syncthreads();
    int B = blockIdx.x / M, sl = blockIdx.x % M;
    int b0 = B * CAP;
    int len = cur[B];
    int seg = (((len + M - 1) / M) + 3) & ~3;
    int lo = b0 + sl * seg;
    int hi = lo + seg, e1 = b0 + len;
    if (hi > e1) hi = e1;
    int n = hi - lo;
    if (n > 0) {
        int nq = n >> 2;
        const uv4* pq = (const uv4*)(pairs + lo);
        for (int i = threadIdx.x; i < nq; i += 1024) {
            uv4 pA = __builtin_nontemporal_load(pq + i);
            int iB = i + 512;
            bool vB = iB < nq;
            u64 e0 = ENC[pA.x & 524287u];
            u64 e1v = ENC[pA.y & 524287u];
            u64 e2 = ENC[pA.z & 524287u];
            u64 e3 = ENC[pA.w & 524287u];
            u64 e4, e5, e6, e7; unsigned d4, d5, d6, d7;
            if (vB) {
                uv4 pB = __builtin_nontemporal_load(pq + iB);
                e4 = ENC[pB.x & 524287u]; d4 = pB.x >> 19;
                e5 = ENC[pB.y & 524287u]; d5 = pB.y >> 19;
                e6 = ENC[pB.z & 524287u]; d6 = pB.z >> 19;
                e7 = ENC[pB.w & 524287u]; d7 = pB.w >> 19;
            }
            atomicAdd(&t[pA.x >> 19], e0);
            atomicAdd(&t[pA.y >> 19], e1v);
            atomicAdd(&t[pA.z >> 19], e2);
            atomicAdd(&t[pA.w >> 19], e3);
            if (vB) {
                atomicAdd(&t[d4], e4);
                atomicAdd(&t[d5], e5);
                atomicAdd(&t[d6], e6);
                atomicAdd(&t[d7], e7);
            }
        }
        int rem = n & 3;
        if ((int)threadIdx.x < rem) {
            unsigned p = pairs[lo + (nq << 2) + threadIdx.x];
            atomicAdd(&t[p >> 19], ENC[p & 524287u]);
        }
    }
    __syncthreads();
    u64* sb = slab + (size_t)blockIdx.x * BSZ;
    for (int j = threadIdx.x; j < BSZ; j += 512)
        __builtin_nontemporal_store(t[j], sb + j);
}

__global__ __launch_bounds__(256) void mergeN2(
    const u64* __restrict__ slab, float* __restrict__ SU, float* __restrict__ SN)
{
    int i = blockIdx.x * 256 + threadIdx.x;
    if (i >= NN) return;
    int B = i >> BSH, low = i & (BSZ - 1);
    u64 s = 0ull;
#pragma unroll
    for (int m = 0; m < M; m++)
        s += __builtin_nontemporal_load(slab + (size_t)(B * M + m) * BSZ + low);
    unsigned sn = (unsigned)(s & 0x3FFFFFull);
    long long sv = (long long)(s - (u64)sn) >> 22;
    float su = (float)((double)sv * 1.4901161193847656e-08);   // 2^-26
    SU[i] = su;
    SN[i] = (float)sn;
}

// ---------------- agg pass 3: 4B gather from SU, f32 atomics -------------------
__global__ __launch_bounds__(512) void agg3k(
    const unsigned* __restrict__ pairs, const int* __restrict__ cur,
    const float* __restrict__ SU, float* __restrict__ slab)
{
    __shared__ float t[BSZ];   // 16 KB
    for (int j = threadIdx.x; j < BSZ; j += 512) t[j] = 0.f;
    __syncthreads();
    int B = blockIdx.x / M, sl = blockIdx.x % M;
    int b0 = B * CAP;
    int len = cur[B];
    int seg = (((len + M - 1) / M) + 3) & ~3;
    int lo = b0 + sl * seg;
    int hi = lo + seg, e1 = b0 + len;
    if (hi > e1) hi = e1;
    int n = hi - lo;
    if (n > 0) {
        int nq = n >> 2;
        const uv4* pq = (const uv4*)(pairs + lo);
        for (int i = threadIdx.x; i < nq; i += 1024) {
            uv4 pA = __builtin_nontemporal_load(pq + i);
            int iB = i + 512;
            bool vB = iB < nq;
            float a0 = SU[pA.x & 524287u];
            float a1 = SU[pA.y & 524287u];
            float a2 = SU[pA.z & 524287u];
            float a3 = SU[pA.w & 524287u];
            float c0, c1, c2, c3; unsigned d4, d5, d6, d7;
            if (vB) {
                uv4 pB = __builtin_nontemporal_load(pq + iB);
                c0 = SU[pB.x & 524287u]; d4 = pB.x >> 19;
                c1 = SU[pB.y & 524287u]; d5 = pB.y >> 19;
                c2 = SU[pB.z & 524287u]; d6 = pB.z >> 19;
                c3 = SU[pB.w & 524287u]; d7 = pB.w >> 19;
            }
            atomicAdd(&t[pA.x >> 19], a0);
            atomicAdd(&t[pA.y >> 19], a1);
            atomicAdd(&t[pA.z >> 19], a2);
            atomicAdd(&t[pA.w >> 19], a3);
            if (vB) {
                atomicAdd(&t[d4], c0);
                atomicAdd(&t[d5], c1);
                atomicAdd(&t[d6], c2);
                atomicAdd(&t[d7], c3);
            }
        }
        int rem = n & 3;
        if ((int)threadIdx.x < rem) {
            unsigned p = pairs[lo + (nq << 2) + threadIdx.x];
            atomicAdd(&t[p >> 19], SU[p & 524287u]);
        }
    }
    __syncthreads();
    float* sb = slab + (size_t)blockIdx.x * BSZ;
    for (int j = threadIdx.x; j < BSZ; j += 512)
        __builtin_nontemporal_store(t[j], sb + j);
}

// ---------------- fused: merge SSU + f64 moments of (u,n,su,sn,ssu) ------------
__global__ __launch_bounds__(256) void m3mom(
    const float* __restrict__ slab, const float2* __restrict__ UN2,
    const float* __restrict__ SU, const float* __restrict__ SN,
    float* __restrict__ SSU, double* __restrict__ dm)
{
    int i = blockIdx.x * 256 + threadIdx.x;
    double z[5] = {0, 0, 0, 0, 0};
    if (i < NN) {
        int B = i >> BSH, low = i & (BSZ - 1);
        float ssu = 0.f;
#pragma unroll
        for (int m = 0; m < M; m++)
            ssu += __builtin_nontemporal_load(slab + (size_t)(B * M + m) * BSZ + low);
        SSU[i] = ssu;
        float2 un = UN2[i];
        z[0] = (double)un.x; z[1] = (double)un.y; z[2] = (double)SU[i];
        z[3] = (double)SN[i]; z[4] = (double)ssu;
    }
    double m[20];
#pragma unroll
    for (int a = 0; a < 5; a++) m[a] = z[a];
    int idx = 5;
#pragma unroll
    for (int a = 0; a < 5; a++)
#pragma unroll
        for (int b = a; b < 5; b++) m[idx++] = z[a] * z[b];

    __shared__ double part[4][20];
    int lane = threadIdx.x & 63, wid = threadIdx.x >> 6;
#pragma unroll
    for (int k = 0; k < 20; k++) {
        double r = waveReduceD(m[k]);
        if (lane == 0) part[wid][k] = r;
    }
    __syncthreads();
    if (threadIdx.x < 20)
        atomicAdd(&dm[threadIdx.x],
                  part[0][threadIdx.x] + part[1][threadIdx.x] +
                  part[2][threadIdx.x] + part[3][threadIdx.x]);
}

// ---------------- K: fold weights + moments into the 4x6 logit matrix ----------
__device__ void mm1010(const float* in, const float* Wa, const float* Wb, float* out)
{
    float t[10];
    for (int m = 0; m < 10; m++) {
        float acc = 0.f;
        for (int k = 0; k < 10; k++) acc += in[k] * Wa[k * 10 + m];
        t[m] = acc;
    }
    for (int j = 0; j < 10; j++) {
        float acc = 0.f;
        for (int m = 0; m < 10; m++) acc += t[m] * Wb[m * 10 + j];
        out[j] = acc;
    }
}

__global__ void constk(
    const float* __restrict__ W1a, const float* __restrict__ b1a,
    const float* __restrict__ W1b, const float* __restrict__ b1b,
    const float* __restrict__ g1, const float* __restrict__ be1,
    const float* __restrict__ W2a, const float* __restrict__ b2a,
    const float* __restrict__ W2b, const float* __restrict__ b2b,
    const float* __restrict__ g2, const float* __restrict__ be2,
    const float* __restrict__ W3a, const float* __restrict__ b3a,
    const float* __restrict__ W3b, const float* __restrict__ b3b,
    const float* __restrict__ g3, const float* __restrict__ be3,
    const float* __restrict__ Wf, const float* __restrict__ bf_,
    const double* __restrict__ dm, float* __restrict__ Lout)
{
    if (threadIdx.x != 0 || blockIdx.x != 0) return;
    const double invN = 1.0 / (double)NN;
    double E[5];
    for (int m = 0; m < 5; m++) E[m] = dm[m] * invN;
    double C[5][5];
    {
        int idx = 5;
        for (int a = 0; a < 5; a++)
            for (int b = a; b < 5; b++) {
                double c = dm[idx++] * invN - E[a] * E[b];
                C[a][b] = c; C[b][a] = c;
            }
    }
    float v[10], c1[10];
    for (int j = 0; j < 10; j++) {
        float av = 0.f, ac = 0.f;
        for (int k = 0; k < 10; k++) {
            av += W1a[k] * W1b[k * 10 + j];
            ac += b1a[k] * W1b[k * 10 + j];
        }
        v[j] = av; c1[j] = ac + b1b[j];
    }
    double Eu = E[0], Vu = C[0][0];
    float p[10], q[10];
    for (int j = 0; j < 10; j++) {
        float var1 = (float)(Vu * (double)v[j] * (double)v[j]);
        float sc1 = g1[j] * rsqrtf(var1 + BN_EPS);
        p[j] = sc1 * v[j];
        q[j] = be1[j] - (float)Eu * p[j];
    }
    float r[10], s[10], d2[10];
    mm1010(p, W2a, W2b, r);
    mm1010(q, W2a, W2b, s);
    for (int j = 0; j < 10; j++) {
        float acc = b2b[j];
        for (int m = 0; m < 10; m++) acc += b2a[m] * W2b[m * 10 + j];
        d2[j] = acc;
    }
    double Ea = E[0] + E[2], Eb = 1.0 + E[1];
    double Va = C[0][0] + 2.0 * C[0][2] + C[2][2];
    double Vb = C[1][1];
    double Cab = C[0][1] + C[2][1];
    float rt[10], st[10], dt[10];
    for (int j = 0; j < 10; j++) {
        double rj = r[j], sj = s[j];
        float var2 = (float)(Va * rj * rj + Vb * sj * sj + 2.0 * Cab * rj * sj);
        float sc2 = g2[j] * rsqrtf(var2 + BN_EPS);
        rt[j] = sc2 * r[j];
        st[j] = sc2 * s[j];
        dt[j] = be2[j] - sc2 * (float)(Ea * rj + Eb * sj);
    }
    float r3[10], s3[10], t3[10], d3[10];
    mm1010(rt, W3a, W3b, r3);
    mm1010(st, W3a, W3b, s3);
    mm1010(dt, W3a, W3b, t3);
    for (int j = 0; j < 10; j++) {
        float acc = b3b[j];
        for (int m = 0; m < 10; m++) acc += b3a[m] * W3b[m * 10 + j];
        d3[j] = acc;
    }
    const double gA[5] = {1, 0, 2, 0, 1};
    const double gB[5] = {0, 2, 0, 1, 0};
    const double gC[5] = {0, 1, 0, 0, 0};
    double EA = E[0] + 2.0 * E[2] + E[4];
    double EB = 1.0 + 2.0 * E[1] + E[3];
    double EC = 1.0 + E[1];
    double VA = 0, VB = 0, VC = 0, CAB = 0, CAC = 0, CBC = 0;
    for (int a = 0; a < 5; a++)
        for (int b = 0; b < 5; b++) {
            double c = C[a][b];
            VA  += gA[a] * gA[b] * c;
            VB  += gB[a] * gB[b] * c;
            VC  += gC[a] * gC[b] * c;
            CAB += gA[a] * gB[b] * c;
            CAC += gA[a] * gC[b] * c;
            CBC += gB[a] * gC[b] * c;
        }
    float rh[10], sh[10], th[10], dh[10];
    for (int j = 0; j < 10; j++) {
        double rj = r3[j], sj = s3[j], tj = t3[j];
        float var3 = (float)(VA * rj * rj + VB * sj * sj + VC * tj * tj
                             + 2.0 * (CAB * rj * sj + CAC * rj * tj + CBC * sj * tj));
        float sc3 = g3[j] * rsqrtf(var3 + BN_EPS);
        rh[j] = sc3 * r3[j];
        sh[j] = sc3 * s3[j];
        th[j] = sc3 * t3[j];
        dh[j] = be3[j] - sc3 * (float)(EA * rj + EB * sj + EC * tj);
    }
    for (int k = 0; k < 4; k++) {
        float Lu = 0, Ln = 0, Lsu = 0, Lsn = 0, Lssu = 0, L0 = bf_[k];
        for (int j = 0; j < 10; j++) {
            float wf1 = Wf[j * 4 + k];
            float wf2 = Wf[(10 + j) * 4 + k];
            float wf3 = Wf[(20 + j) * 4 + k];
            Lu   += p[j] * wf1 + rt[j] * wf2 + rh[j] * wf3;
            Ln   += st[j] * wf2 + (2.f * sh[j] + th[j]) * wf3;
            Lsu  += rt[j] * wf2 + 2.f * rh[j] * wf3;
            Lsn  += sh[j] * wf3;
            Lssu += rh[j] * wf3;
            L0   += q[j] * wf1 + (st[j] + dt[j]) * wf2 + (sh[j] + th[j] + dh[j]) * wf3;
        }
        Lout[0 * 4 + k] = Lu;  Lout[1 * 4 + k] = Ln;   Lout[2 * 4 + k] = Lsu;
        Lout[3 * 4 + k] = Lsn; Lout[4 * 4 + k] = Lssu; Lout[5 * 4 + k] = L0;
    }
}

// ---------------- F: logits -> softmax -> s (f32 out + bf16 side table) --------
__global__ __launch_bounds__(256) void finalk(
    const float2* __restrict__ UN2, const float* __restrict__ SU,
    const float* __restrict__ SN, const float* __restrict__ SSU,
    const float* __restrict__ L,
    float4* __restrict__ sout, ushort4* __restrict__ sbf)
{
    __shared__ float sL[24];
    if (threadIdx.x < 24) sL[threadIdx.x] = L[threadIdx.x];
    __syncthreads();
    int i = blockIdx.x * 256 + threadIdx.x;
    if (i >= NN) return;
    float2 un = UN2[i];
    float u = un.x, n = un.y, su = SU[i], sn = SN[i], ssu = SSU[i];
    float lg[4];
#pragma unroll
    for (int k = 0; k < 4; k++)
        lg[k] = sL[k] * u + sL[4 + k] * n + sL[8 + k] * su
              + sL[12 + k] * sn + sL[16 + k] * ssu + sL[20 + k];
    float mx = fmaxf(fmaxf(lg[0], lg[1]), fmaxf(lg[2], lg[3]));
    float e0 = __expf(lg[0] - mx), e1 = __expf(lg[1] - mx);
    float e2 = __expf(lg[2] - mx), e3 = __expf(lg[3] - mx);
    float inv = 1.f / (e0 + e1 + e2 + e3);
    float s0 = e0 * inv, s1 = e1 * inv, s2 = e2 * inv, s3 = e3 * inv;
    fv4 o = {s0, s1, s2, s3};
    __builtin_nontemporal_store(o, (fv4*)sout + i);
    ushort4 pk; pk.x = f2u(s0); pk.y = f2u(s1); pk.z = f2u(s2); pk.w = f2u(s3);
    sbf[i] = pk;
}

// ---------------- modk: dst-side s in LDS, natural pipelining, NO fence --------
__device__ __forceinline__ void modacc(u64 ua, u64 ub, float we, float* acc) {
    float ax = u2f((unsigned short)ua),         ay = u2f((unsigned short)(ua >> 16));
    float az = u2f((unsigned short)(ua >> 32)), aw = u2f((unsigned short)(ua >> 48));
    float bx = u2f((unsigned short)ub),         by = u2f((unsigned short)(ub >> 16));
    float bz = u2f((unsigned short)(ub >> 32)), bw = u2f((unsigned short)(ub >> 48));
    acc[0] += we;
    acc[1] += we * (ax * bx + ay * by + az * bz + aw * bw);
    acc[2] += we * ax; acc[3] += we * ay;
    acc[4] += we * az; acc[5] += we * aw;
}

__global__ __launch_bounds__(512) void modk(
    const unsigned* __restrict__ pairs, const unsigned short* __restrict__ wp,
    const int* __restrict__ cur, const u64* __restrict__ sbfU,
    float* __restrict__ scal)
{
    __shared__ u64 sS[BSZ];   // 32 KB: this bucket's dst-side s values
    int B = blockIdx.x / M, sl = blockIdx.x % M;
    for (int j = threadIdx.x; j < BSZ; j += 512) {
        int g = (B << BSH) + j;
        sS[j] = (g < NN) ? sbfU[g] : 0ull;
    }
    __syncthreads();
    int b0 = B * CAP;
    int len = cur[B];
    int seg = (((len + M - 1) / M) + 3) & ~3;
    int lo = b0 + sl * seg;
    int hi = lo + seg, e1 = b0 + len;
    if (hi > e1) hi = e1;
    int n = hi - lo;
    float acc[6] = {0, 0, 0, 0, 0, 0};
    if (n > 0) {
        int nq = n >> 2;
        const uv4* pq = (const uv4*)(pairs + lo);
        const u64* wq = (const u64*)(wp + lo);
        for (int i = threadIdx.x; i < nq; i += 1024) {
            uv4 pA = __builtin_nontemporal_load(pq + i);
            u64 wA = __builtin_nontemporal_load(wq + i);
            int iB = i + 512;
            bool vB = iB < nq;
            u64 a0 = sbfU[pA.x & 524287u];
            u64 a1 = sbfU[pA.y & 524287u];
            u64 a2 = sbfU[pA.z & 524287u];
            u64 a3 = sbfU[pA.w & 524287u];
            uv4 pB; u64 wB; u64 a4, a5, a6, a7;
            if (vB) {
                pB = __builtin_nontemporal_load(pq + iB);
                wB = __builtin_nontemporal_load(wq + iB);
                a4 = sbfU[pB.x & 524287u];
                a5 = sbfU[pB.y & 524287u];
                a6 = sbfU[pB.z & 524287u];
                a7 = sbfU[pB.w & 524287u];
            }
            modacc(a0, sS[pA.x >> 19], u2f((unsigned short)wA),         acc);
            modacc(a1, sS[pA.y >> 19], u2f((unsigned short)(wA >> 16)), acc);
            modacc(a2, sS[pA.z >> 19], u2f((unsigned short)(wA >> 32)), acc);
            modacc(a3, sS[pA.w >> 19], u2f((unsigned short)(wA >> 48)), acc);
            if (vB) {
                modacc(a4, sS[pB.x >> 19], u2f((unsigned short)wB),         acc);
                modacc(a5, sS[pB.y >> 19], u2f((unsigned short)(wB >> 16)), acc);
                modacc(a6, sS[pB.z >> 19], u2f((unsigned short)(wB >> 32)), acc);
                modacc(a7, sS[pB.w >> 19], u2f((unsigned short)(wB >> 48)), acc);
            }
        }
        int rem = n & 3;
        if ((int)threadIdx.x < rem) {
            int idx = lo + (nq << 2) + threadIdx.x;
            unsigned p = pairs[idx];
            modacc(sbfU[p & 524287u], sS[p >> 19], u2f(wp[idx]), acc);
        }
    }
    __shared__ float part[8][6];
    int lane = threadIdx.x & 63, wid = threadIdx.x >> 6;
#pragma unroll
    for (int k = 0; k < 6; k++) {
        float r = waveReduceF(acc[k]);
        if (lane == 0) part[wid][k] = r;
    }
    __syncthreads();
    if (threadIdx.x < 6) {
        float vsum = 0.f;
#pragma unroll
        for (int wdi = 0; wdi < 8; wdi++) vsum += part[wdi][threadIdx.x];
        int off = (threadIdx.x == 0) ? 128 : (threadIdx.x == 1 ? 129 : 130 + threadIdx.x);
        atomicAdd(&scal[off], vsum);
    }
}

// ---------------- q ------------------------------------------------------------
__global__ void qk(const float* __restrict__ scal, float* __restrict__ out)
{
    if (threadIdx.x == 0) {
        float inv = 1.f / scal[128];
        float posv = scal[129] * inv;
        float acc = 0.f;
#pragma unroll
        for (int k = 0; k < 4; k++) {
            float d = scal[132 + k] * inv;
            acc += d * d;
        }
        out[(size_t)NN * 4] = posv - acc;
    }
}

extern "C" void kernel_launch(void* const* d_in, const int* in_sizes, int n_in,
                              void* d_out, int out_size, void* d_ws, size_t ws_size,
                              hipStream_t stream) {
    const float* x  = (const float*)d_in[0];
    const int*  ei  = (const int*)d_in[1];
    const int*  src = ei;
    const int*  dst = ei + NE;
    const float* w   = (const float*)d_in[2];
    const float* W1a = (const float*)d_in[3];  const float* b1a = (const float*)d_in[4];
    const float* W1b = (const float*)d_in[5];  const float* b1b = (const float*)d_in[6];
    const float* g1  = (const float*)d_in[7];  const float* be1 = (const float*)d_in[8];
    const float* W2a = (const float*)d_in[9];  const float* b2a = (const float*)d_in[10];
    const float* W2b = (const float*)d_in[11]; const float* b2b = (const float*)d_in[12];
    const float* g2  = (const float*)d_in[13]; const float* be2 = (const float*)d_in[14];
    const float* W3a = (const float*)d_in[15]; const float* b3a = (const float*)d_in[16];
    const float* W3b = (const float*)d_in[17]; const float* b3b = (const float*)d_in[18];
    const float* g3  = (const float*)d_in[19]; const float* be3 = (const float*)d_in[20];
    const float* Wf  = (const float*)d_in[21]; const float* bfb = (const float*)d_in[22];

    // workspace layout:
    //  floats sc[0..1023]: two_m@128, pos@129, ds@132..135, L@160..183,
    //    dm (20 doubles) @ float-idx 384 (byte 1536),
    //    cur ints @ sci[832..954]  (all inside the 4KB memset region)
    //  byte 4096: pairs uint[NB*CAP] (34.3MB) | wp ushort[NB*CAP] (17.1MB) |
    //    slab (32.25MB, u64[NAGG*BSZ] rounds 1/2, float[NAGG*BSZ] round 3) |
    //    UN2 float2[NN] | SU float[NN] | SN float[NN] | SSU float[NN] |
    //    sbf ushort4[NN] | ENC u64[NN]
    float*  sc   = (float*)d_ws;
    int*    sci  = (int*)d_ws;
    double* dm   = (double*)(sc + 384);
    unsigned* pairs = (unsigned*)(sc + 1024);
    unsigned short* wp = (unsigned short*)(pairs + (size_t)NB * CAP);
    float*  slab = (float*)(wp + (size_t)NB * CAP);
    u64*    slabU = (u64*)slab;
    float2* UN2  = (float2*)(slab + (size_t)NAGG * 2 * BSZ);
    float*  SU   = (float*)(UN2 + NN);
    float*  SN   = SU + NN;
    float*  SSU  = SN + NN;
    ushort4* sbf = (ushort4*)(SSU + NN);
    u64*    ENC  = (u64*)(sbf + NN);
    float*  sout = (float*)d_out;

    const int NB_N  = (NN + 255) / 256;
    const int NB_EQ = (NE / 4 + 1023) / 1024;   // 1954 blocks over int4-quads

    hipMemsetAsync(sc, 0, 4096, stream);

    // bucketize once (dst -> 123 fixed-capacity buckets), block counting sort
    scatterk<<<NB_EQ, 512, 0, stream>>>((const iv4*)src, (const iv4*)dst,
                                        (const fv4*)w, sci + 832, pairs, wp);

    // three aggregation rounds; packed u64 atomics in rounds 1/2
    agg1k<<<NAGG, 512, 0, stream>>>(pairs, sci + 832, x, slabU);
    mergeN1<<<NB_N, 256, 0, stream>>>(slabU, x, UN2, ENC);
    agg2k<<<NAGG, 512, 0, stream>>>(pairs, sci + 832, ENC, slabU);
    mergeN2<<<NB_N, 256, 0, stream>>>(slabU, SU, SN);
    agg3k<<<NAGG, 512, 0, stream>>>(pairs, sci + 832, SU, slab);
    m3mom<<<NB_N, 256, 0, stream>>>(slab, UN2, SU, SN, SSU, dm);

    // closed-form logit matrix (1 block, reg pressure isolated here)
    constk<<<1, 64, 0, stream>>>(W1a, b1a, W1b, b1b, g1, be1,
                                 W2a, b2a, W2b, b2b, g2, be2,
                                 W3a, b3a, W3b, b3b, g3, be3,
                                 Wf, bfb, dm, sc + 160);

    // softmax -> modularity -> q (tiny separate kernel; fences are poison)
    finalk<<<NB_N, 256, 0, stream>>>(UN2, SU, SN, SSU, sc + 160, (float4*)sout, sbf);
    modk<<<NAGG, 512, 0, stream>>>(pairs, wp, sci + 832, (const u64*)sbf, sc);
    qk<<<1, 64, 0, stream>>>(sc, sout);
}

// Round 8
// 480.491 us; speedup vs baseline: 2.3239x; 1.0524x over previous
//
#include <hip/hip_runtime.h>
#include <hip/hip_bf16.h>

#define NN 500000
#define NE 8000000
#define NB 123           // buckets of 4096 nodes: 123*4096 = 503808 >= NN
#define BSH 12
#define BSZ 4096
#define CAP 69632        // fixed bucket capacity (65536 mean + 16 sigma), mult of 4
#define M 8              // slices (blocks) per bucket
#define NAGG (NB * M)    // 984 blocks
#define BN_EPS 1e-5f

typedef unsigned uv4 __attribute__((ext_vector_type(4)));
typedef int iv4 __attribute__((ext_vector_type(4)));
typedef float fv4 __attribute__((ext_vector_type(4)));
typedef unsigned long long u64;

__device__ __forceinline__ float waveReduceF(float v) {
#pragma unroll
    for (int o = 32; o > 0; o >>= 1) v += __shfl_down(v, o, 64);
    return v;
}
__device__ __forceinline__ double waveReduceD(double v) {
#pragma unroll
    for (int o = 32; o > 0; o >>= 1) v += __shfl_down(v, o, 64);
    return v;
}
__device__ __forceinline__ float u2f(unsigned short u) {
    return __bfloat162float(__builtin_bit_cast(__hip_bfloat16, u));
}
__device__ __forceinline__ unsigned short f2u(float f) {
    return __builtin_bit_cast(unsigned short, __float2bfloat16(f));
}
// pack x-sample into (fixed<<20)+count1.  |x|<6 -> x*2^28 < 2^31 (int ok)
__device__ __forceinline__ u64 pk1(float v) {
    int iv = (int)rintf(v * 268435456.f);              // 2^28
    return ((u64)(long long)iv << 20) + 1ull;
}

// ---------------- bucketize: block counting sort, coalesced emit ---------------
__global__ __launch_bounds__(512) void scatterk(
    const iv4* __restrict__ src4, const iv4* __restrict__ dst4,
    const fv4* __restrict__ w4, int* __restrict__ cur,
    unsigned* __restrict__ pairs, unsigned short* __restrict__ wp)
{
    __shared__ unsigned sEnt[4096];        // 16 KB
    __shared__ unsigned short sW[4096];    // 8 KB
    __shared__ unsigned char sB[4096];     // 4 KB
    __shared__ int h[8][128];              // per-wave histograms
    __shared__ int wOff[8][128];           // cross-wave prefix per bucket
    __shared__ int bOff[128];              // block-local bucket prefix
    __shared__ int lb[128];                // global base for this block per bucket
    __shared__ int tot[128];

    int tid = threadIdx.x, wv = tid >> 6;
    for (int j = tid; j < 8 * 128; j += 512) (&h[0][0])[j] = 0;
    __syncthreads();

    unsigned en[8]; unsigned short wb[8]; int rb[8];   // rk<<8 | b, or -1
#pragma unroll
    for (int k = 0; k < 2; k++) {
        int q = blockIdx.x * 1024 + k * 512 + tid;
        if (q < NE / 4) {
            iv4 s4 = __builtin_nontemporal_load(src4 + q);
            iv4 d4 = __builtin_nontemporal_load(dst4 + q);
            fv4 ww = __builtin_nontemporal_load(w4 + q);
            int ss[4] = {s4.x, s4.y, s4.z, s4.w};
            int dd[4] = {d4.x, d4.y, d4.z, d4.w};
            float fw[4] = {ww.x, ww.y, ww.z, ww.w};
#pragma unroll
            for (int i = 0; i < 4; i++) {
                int d = dd[i], b = d >> BSH;
                en[k * 4 + i] = ((unsigned)(d & (BSZ - 1)) << 19) | (unsigned)ss[i];
                wb[k * 4 + i] = f2u(fw[i]);
                int rk = atomicAdd(&h[wv][b], 1);
                rb[k * 4 + i] = (rk << 8) | b;
            }
        } else {
#pragma unroll
            for (int i = 0; i < 4; i++) rb[k * 4 + i] = -1;
        }
    }
    __syncthreads();
    if (tid < NB) {
        int acc = 0;
#pragma unroll
        for (int w = 0; w < 8; w++) { wOff[w][tid] = acc; acc += h[w][tid]; }
        tot[tid] = acc;
        lb[tid] = tid * CAP + atomicAdd(&cur[tid], acc);
    }
    __syncthreads();
    // wave-parallel exclusive prefix of tot -> bOff (lanes 0..63, 2 elems each)
    if (tid < 64) {
        int lane = tid;
        int a = (2 * lane < NB) ? tot[2 * lane] : 0;
        int b = (2 * lane + 1 < NB) ? tot[2 * lane + 1] : 0;
        int s = a + b;
#pragma unroll
        for (int o = 1; o < 64; o <<= 1) {
            int t = __shfl_up(s, o, 64);
            if (lane >= o) s += t;
        }
        int excl = s - (a + b);
        bOff[2 * lane] = excl;
        bOff[2 * lane + 1] = excl + a;
    }
    __syncthreads();
#pragma unroll
    for (int k = 0; k < 8; k++) {
        if (rb[k] >= 0) {
            int b = rb[k] & 255, rk = rb[k] >> 8;
            int pos = bOff[b] + wOff[wv][b] + rk;
            sEnt[pos] = en[k]; sW[pos] = wb[k]; sB[pos] = (unsigned char)b;
        }
    }
    __syncthreads();
    int nE = NE - blockIdx.x * 4096; if (nE > 4096) nE = 4096;
    for (int j = tid; j < nE; j += 512) {
        int b = sB[j];
        int glob = lb[b] + (j - bOff[b]);
        __builtin_nontemporal_store(sEnt[j], pairs + glob);
        __builtin_nontemporal_store(sW[j], wp + glob);
    }
}

// ---------------- agg pass 1: packed u64 (x<<20 | count), natural pipelining ---
__global__ __launch_bounds__(512) void agg1k(
    const unsigned* __restrict__ pairs, const int* __restrict__ cur,
    const float* __restrict__ x, u64* __restrict__ slab)
{
    __shared__ u64 t[BSZ];   // 32 KB
    for (int j = threadIdx.x; j < BSZ; j += 512) t[j] = 0ull;
    __syncthreads();
    int B = blockIdx.x / M, sl = blockIdx.x % M;
    int b0 = B * CAP;
    int len = cur[B];
    int seg = (((len + M - 1) / M) + 3) & ~3;
    int lo = b0 + sl * seg;
    int hi = lo + seg, e1 = b0 + len;
    if (hi > e1) hi = e1;
    int n = hi - lo;
    if (n > 0) {
        int nq = n >> 2;
        const uv4* pq = (const uv4*)(pairs + lo);
        for (int i = threadIdx.x; i < nq; i += 1024) {
            uv4 pA = __builtin_nontemporal_load(pq + i);
            int iB = i + 512;
            bool vB = iB < nq;
            float a0 = x[pA.x & 524287u];
            float a1 = x[pA.y & 524287u];
            float a2 = x[pA.z & 524287u];
            float a3 = x[pA.w & 524287u];
            float c0, c1, c2, c3; unsigned d4, d5, d6, d7;
            if (vB) {
                uv4 pB = __builtin_nontemporal_load(pq + iB);
                c0 = x[pB.x & 524287u]; d4 = pB.x >> 19;
                c1 = x[pB.y & 524287u]; d5 = pB.y >> 19;
                c2 = x[pB.z & 524287u]; d6 = pB.z >> 19;
                c3 = x[pB.w & 524287u]; d7 = pB.w >> 19;
            }
            atomicAdd(&t[pA.x >> 19], pk1(a0));
            atomicAdd(&t[pA.y >> 19], pk1(a1));
            atomicAdd(&t[pA.z >> 19], pk1(a2));
            atomicAdd(&t[pA.w >> 19], pk1(a3));
            if (vB) {
                atomicAdd(&t[d4], pk1(c0));
                atomicAdd(&t[d5], pk1(c1));
                atomicAdd(&t[d6], pk1(c2));
                atomicAdd(&t[d7], pk1(c3));
            }
        }
        int rem = n & 3;
        if ((int)threadIdx.x < rem) {
            unsigned p = pairs[lo + (nq << 2) + threadIdx.x];
            atomicAdd(&t[p >> 19], pk1(x[p & 524287u]));
        }
    }
    __syncthreads();
    u64* sb = slab + (size_t)blockIdx.x * BSZ;
    for (int j = threadIdx.x; j < BSZ; j += 512)
        __builtin_nontemporal_store(t[j], sb + j);
}

// decode: count in low 20 bits, x-sum (2^-28 fixed) above.  Also emit the
// pre-packed agg2 operand ENC = (u*2^26)<<22 + n  (one 8B gather, one u64 atomic)
__global__ __launch_bounds__(256) void mergeN1(
    const u64* __restrict__ slab, const float* __restrict__ x,
    float2* __restrict__ UN2, u64* __restrict__ ENC)
{
    int i = blockIdx.x * 256 + threadIdx.x;
    if (i >= NN) return;
    int B = i >> BSH, low = i & (BSZ - 1);
    u64 s = 0ull;
#pragma unroll
    for (int m = 0; m < M; m++)
        s += __builtin_nontemporal_load(slab + (size_t)(B * M + m) * BSZ + low);
    unsigned cn = (unsigned)(s & 0xFFFFFull);
    long long sv = (long long)(s - (u64)cn) >> 20;
    float u = x[i] + (float)((double)sv * 3.725290298461914e-09);  // 2^-28
    UN2[i] = make_float2(u, (float)cn);
    long long iu = (long long)rintf(u * 67108864.f);               // 2^26
    ENC[i] = ((u64)iu << 22) + (u64)cn;
}

// ---------------- agg pass 2: gather pre-packed ENC, single u64 atomic ---------
__global__ __launch_bounds__(512) void agg2k(
    const unsigned* __restrict__ pairs, const int* __restrict__ cur,
    const u64* __restrict__ ENC, u64* __restrict__ slab)
{
    __shared__ u64 t[BSZ];   // 32 KB
    for (int j = threadIdx.x; j < BSZ; j += 512) t[j] = 0ull;
    __syncthreads();
    int B = blockIdx.x / M, sl = blockIdx.x % M;
    int b0 = B * CAP;
    int len = cur[B];
    int seg = (((len + M - 1) / M) + 3) & ~3;
    int lo = b0 + sl * seg;
    int hi = lo + seg, e1 = b0 + len;
    if (hi > e1) hi = e1;
    int n = hi - lo;
    if (n > 0) {
        int nq = n >> 2;
        const uv4* pq = (const uv4*)(pairs + lo);
        for (int i = threadIdx.x; i < nq; i += 1024) {
            uv4 pA = __builtin_nontemporal_load(pq + i);
            int iB = i + 512;
            bool vB = iB < nq;
            u64 e0 = ENC[pA.x & 524287u];
            u64 e1v = ENC[pA.y & 524287u];
            u64 e2 = ENC[pA.z & 524287u];
            u64 e3 = ENC[pA.w & 524287u];
            u64 e4, e5, e6, e7; unsigned d4, d5, d6, d7;
            if (vB) {
                uv4 pB = __builtin_nontemporal_load(pq + iB);
                e4 = ENC[pB.x & 524287u]; d4 = pB.x >> 19;
                e5 = ENC[pB.y & 524287u]; d5 = pB.y >> 19;
                e6 = ENC[pB.z & 524287u]; d6 = pB.z >> 19;
                e7 = ENC[pB.w & 524287u]; d7 = pB.w >> 19;
            }
            atomicAdd(&t[pA.x >> 19], e0);
            atomicAdd(&t[pA.y >> 19], e1v);
            atomicAdd(&t[pA.z >> 19], e2);
            atomicAdd(&t[pA.w >> 19], e3);
            if (vB) {
                atomicAdd(&t[d4], e4);
                atomicAdd(&t[d5], e5);
                atomicAdd(&t[d6], e6);
                atomicAdd(&t[d7], e7);
            }
        }
        int rem = n & 3;
        if ((int)threadIdx.x < rem) {
            unsigned p = pairs[lo + (nq << 2) + threadIdx.x];
            atomicAdd(&t[p >> 19], ENC[p & 524287u]);
        }
    }
    __syncthreads();
    u64* sb = slab + (size_t)blockIdx.x * BSZ;
    for (int j = threadIdx.x; j < BSZ; j += 512)
        __builtin_nontemporal_store(t[j], sb + j);
}

__global__ __launch_bounds__(256) void mergeN2(
    const u64* __restrict__ slab, float* __restrict__ SU, float* __restrict__ SN)
{
    int i = blockIdx.x * 256 + threadIdx.x;
    if (i >= NN) return;
    int B = i >> BSH, low = i & (BSZ - 1);
    u64 s = 0ull;
#pragma unroll
    for (int m = 0; m < M; m++)
        s += __builtin_nontemporal_load(slab + (size_t)(B * M + m) * BSZ + low);
    unsigned sn = (unsigned)(s & 0x3FFFFFull);
    long long sv = (long long)(s - (u64)sn) >> 22;
    float su = (float)((double)sv * 1.4901161193847656e-08);   // 2^-26
    SU[i] = su;
    SN[i] = (float)sn;
}

// ---------------- agg pass 3: 4B gather from SU, f32 atomics -------------------
__global__ __launch_bounds__(512) void agg3k(
    const unsigned* __restrict__ pairs, const int* __restrict__ cur,
    const float* __restrict__ SU, float* __restrict__ slab)
{
    __shared__ float t[BSZ];   // 16 KB
    for (int j = threadIdx.x; j < BSZ; j += 512) t[j] = 0.f;
    __syncthreads();
    int B = blockIdx.x / M, sl = blockIdx.x % M;
    int b0 = B * CAP;
    int len = cur[B];
    int seg = (((len + M - 1) / M) + 3) & ~3;
    int lo = b0 + sl * seg;
    int hi = lo + seg, e1 = b0 + len;
    if (hi > e1) hi = e1;
    int n = hi - lo;
    if (n > 0) {
        int nq = n >> 2;
        const uv4* pq = (const uv4*)(pairs + lo);
        for (int i = threadIdx.x; i < nq; i += 1024) {
            uv4 pA = __builtin_nontemporal_load(pq + i);
            int iB = i + 512;
            bool vB = iB < nq;
            float a0 = SU[pA.x & 524287u];
            float a1 = SU[pA.y & 524287u];
            float a2 = SU[pA.z & 524287u];
            float a3 = SU[pA.w & 524287u];
            float c0, c1, c2, c3; unsigned d4, d5, d6, d7;
            if (vB) {
                uv4 pB = __builtin_nontemporal_load(pq + iB);
                c0 = SU[pB.x & 524287u]; d4 = pB.x >> 19;
                c1 = SU[pB.y & 524287u]; d5 = pB.y >> 19;
                c2 = SU[pB.z & 524287u]; d6 = pB.z >> 19;
                c3 = SU[pB.w & 524287u]; d7 = pB.w >> 19;
            }
            atomicAdd(&t[pA.x >> 19], a0);
            atomicAdd(&t[pA.y >> 19], a1);
            atomicAdd(&t[pA.z >> 19], a2);
            atomicAdd(&t[pA.w >> 19], a3);
            if (vB) {
                atomicAdd(&t[d4], c0);
                atomicAdd(&t[d5], c1);
                atomicAdd(&t[d6], c2);
                atomicAdd(&t[d7], c3);
            }
        }
        int rem = n & 3;
        if ((int)threadIdx.x < rem) {
            unsigned p = pairs[lo + (nq << 2) + threadIdx.x];
            atomicAdd(&t[p >> 19], SU[p & 524287u]);
        }
    }
    __syncthreads();
    float* sb = slab + (size_t)blockIdx.x * BSZ;
    for (int j = threadIdx.x; j < BSZ; j += 512)
        __builtin_nontemporal_store(t[j], sb + j);
}

// ---------------- fused: merge SSU + f64 moments of (u,n,su,sn,ssu) ------------
__global__ __launch_bounds__(256) void m3mom(
    const float* __restrict__ slab, const float2* __restrict__ UN2,
    const float* __restrict__ SU, const float* __restrict__ SN,
    float* __restrict__ SSU, double* __restrict__ dm)
{
    int i = blockIdx.x * 256 + threadIdx.x;
    double z[5] = {0, 0, 0, 0, 0};
    if (i < NN) {
        int B = i >> BSH, low = i & (BSZ - 1);
        float ssu = 0.f;
#pragma unroll
        for (int m = 0; m < M; m++)
            ssu += __builtin_nontemporal_load(slab + (size_t)(B * M + m) * BSZ + low);
        SSU[i] = ssu;
        float2 un = UN2[i];
        z[0] = (double)un.x; z[1] = (double)un.y; z[2] = (double)SU[i];
        z[3] = (double)SN[i]; z[4] = (double)ssu;
    }
    double m[20];
#pragma unroll
    for (int a = 0; a < 5; a++) m[a] = z[a];
    int idx = 5;
#pragma unroll
    for (int a = 0; a < 5; a++)
#pragma unroll
        for (int b = a; b < 5; b++) m[idx++] = z[a] * z[b];

    __shared__ double part[4][20];
    int lane = threadIdx.x & 63, wid = threadIdx.x >> 6;
#pragma unroll
    for (int k = 0; k < 20; k++) {
        double r = waveReduceD(m[k]);
        if (lane == 0) part[wid][k] = r;
    }
    __syncthreads();
    if (threadIdx.x < 20)
        atomicAdd(&dm[threadIdx.x],
                  part[0][threadIdx.x] + part[1][threadIdx.x] +
                  part[2][threadIdx.x] + part[3][threadIdx.x]);
}

// ---------------- K: wave-parallel fold of weights + moments -> 4x6 logits -----
// LDS layout (floats): W1a@0(10) b1a@10 W1b@20(100) b1b@120 g1@130 be1@140
//   W2a@150(100) b2a@250 W2b@260(100) b2b@360 g2@370 be2@380
//   W3a@390(100) b3a@490 W3b@500(100) b3b@600 g3@610 be3@620
//   Wf@630(120) bf@750(4)
__global__ __launch_bounds__(64) void constk(
    const float* __restrict__ W1a, const float* __restrict__ b1a,
    const float* __restrict__ W1b, const float* __restrict__ b1b,
    const float* __restrict__ g1, const float* __restrict__ be1,
    const float* __restrict__ W2a, const float* __restrict__ b2a,
    const float* __restrict__ W2b, const float* __restrict__ b2b,
    const float* __restrict__ g2, const float* __restrict__ be2,
    const float* __restrict__ W3a, const float* __restrict__ b3a,
    const float* __restrict__ W3b, const float* __restrict__ b3b,
    const float* __restrict__ g3, const float* __restrict__ be3,
    const float* __restrict__ Wf, const float* __restrict__ bf_,
    const double* __restrict__ dm, float* __restrict__ Lout)
{
    __shared__ float sw[768];
    __shared__ double sdm[20];
    __shared__ float vv[9][10];   // p,q,rt,st,dt,rh,sh,th,dh
    int t = threadIdx.x;
    if (t < 10) {
        sw[0 + t] = W1a[t];  sw[10 + t] = b1a[t];  sw[120 + t] = b1b[t];
        sw[130 + t] = g1[t]; sw[140 + t] = be1[t];
        sw[250 + t] = b2a[t]; sw[360 + t] = b2b[t];
        sw[370 + t] = g2[t]; sw[380 + t] = be2[t];
        sw[490 + t] = b3a[t]; sw[600 + t] = b3b[t];
        sw[610 + t] = g3[t]; sw[620 + t] = be3[t];
    }
    for (int i = t; i < 100; i += 64) {
        sw[20 + i]  = W1b[i];
        sw[150 + i] = W2a[i];
        sw[260 + i] = W2b[i];
        sw[390 + i] = W3a[i];
        sw[500 + i] = W3b[i];
    }
    for (int i = t; i < 120; i += 64) sw[630 + i] = Wf[i];
    if (t < 4)  sw[750 + t] = bf_[t];
    if (t < 20) sdm[t] = dm[t];
    __syncthreads();

    // every lane: moments E, covariance C (registers, f64) — cheap redundancy
    const double invN = 1.0 / (double)NN;
    double E[5];
#pragma unroll
    for (int m = 0; m < 5; m++) E[m] = sdm[m] * invN;
    double C[5][5];
    {
        int idx = 5;
#pragma unroll
        for (int a = 0; a < 5; a++)
#pragma unroll
            for (int b = a; b < 5; b++) {
                double c = sdm[idx++] * invN - E[a] * E[b];
                C[a][b] = c; C[b][a] = c;
            }
    }
    int j = t;   // lane j owns output column j (j<10)
    if (j < 10) {
        float vj = 0.f;
        for (int k = 0; k < 10; k++) vj += sw[0 + k] * sw[20 + k * 10 + j];
        float var1 = (float)(C[0][0] * (double)vj * (double)vj);
        float sc1 = sw[130 + j] * rsqrtf(var1 + BN_EPS);
        float pj = sc1 * vj;
        float qj = sw[140 + j] - (float)E[0] * pj;
        vv[0][j] = pj; vv[1][j] = qj;
    }
    __syncthreads();
    if (j < 10) {
        float tp[10], tq[10];
        for (int m = 0; m < 10; m++) {
            float ap = 0.f, aq = 0.f;
            for (int k = 0; k < 10; k++) {
                float w = sw[150 + k * 10 + m];
                ap += vv[0][k] * w; aq += vv[1][k] * w;
            }
            tp[m] = ap; tq[m] = aq;
        }
        float rj = 0.f, sj = 0.f;
        for (int m = 0; m < 10; m++) {
            float w = sw[260 + m * 10 + j];
            rj += tp[m] * w; sj += tq[m] * w;
        }
        double Ea = E[0] + E[2], Eb = 1.0 + E[1];
        double Va = C[0][0] + 2.0 * C[0][2] + C[2][2];
        double Vb = C[1][1];
        double Cab = C[0][1] + C[2][1];
        double rjd = rj, sjd = sj;
        float var2 = (float)(Va * rjd * rjd + Vb * sjd * sjd + 2.0 * Cab * rjd * sjd);
        float sc2 = sw[370 + j] * rsqrtf(var2 + BN_EPS);
        vv[2][j] = sc2 * rj;
        vv[3][j] = sc2 * sj;
        vv[4][j] = sw[380 + j] - sc2 * (float)(Ea * rjd + Eb * sjd);
    }
    __syncthreads();
    if (j < 10) {
        float tr[10], ts[10], tt[10];
        for (int m = 0; m < 10; m++) {
            float ar = 0.f, as = 0.f, at = 0.f;
            for (int k = 0; k < 10; k++) {
                float w = sw[390 + k * 10 + m];
                ar += vv[2][k] * w; as += vv[3][k] * w; at += vv[4][k] * w;
            }
            tr[m] = ar; ts[m] = as; tt[m] = at;
        }
        float r3 = 0.f, s3 = 0.f, t3 = 0.f;
        for (int m = 0; m < 10; m++) {
            float w = sw[500 + m * 10 + j];
            r3 += tr[m] * w; s3 += ts[m] * w; t3 += tt[m] * w;
        }
        const double gA[5] = {1, 0, 2, 0, 1};
        const double gB[5] = {0, 2, 0, 1, 0};
        const double gC[5] = {0, 1, 0, 0, 0};
        double EA = E[0] + 2.0 * E[2] + E[4];
        double EB = 1.0 + 2.0 * E[1] + E[3];
        double EC = 1.0 + E[1];
        double VA = 0, VB = 0, VC = 0, CAB = 0, CAC = 0, CBC = 0;
        for (int a = 0; a < 5; a++)
            for (int b = 0; b < 5; b++) {
                double c = C[a][b];
                VA  += gA[a] * gA[b] * c;
                VB  += gB[a] * gB[b] * c;
                VC  += gC[a] * gC[b] * c;
                CAB += gA[a] * gB[b] * c;
                CAC += gA[a] * gC[b] * c;
                CBC += gB[a] * gC[b] * c;
            }
        double r3d = r3, s3d = s3, t3d = t3;
        float var3 = (float)(VA * r3d * r3d + VB * s3d * s3d + VC * t3d * t3d
                             + 2.0 * (CAB * r3d * s3d + CAC * r3d * t3d + CBC * s3d * t3d));
        float sc3 = sw[610 + j] * rsqrtf(var3 + BN_EPS);
        vv[5][j] = sc3 * r3;
        vv[6][j] = sc3 * s3;
        vv[7][j] = sc3 * t3;
        vv[8][j] = sw[620 + j] - sc3 * (float)(EA * r3d + EB * s3d + EC * t3d);
    }
    __syncthreads();
    if (t < 4) {
        int k = t;
        float Lu = 0, Ln = 0, Lsu = 0, Lsn = 0, Lssu = 0, L0 = sw[750 + k];
        for (int j2 = 0; j2 < 10; j2++) {
            float wf1 = sw[630 + j2 * 4 + k];
            float wf2 = sw[630 + (10 + j2) * 4 + k];
            float wf3 = sw[630 + (20 + j2) * 4 + k];
            Lu   += vv[0][j2] * wf1 + vv[2][j2] * wf2 + vv[5][j2] * wf3;
            Ln   += vv[3][j2] * wf2 + (2.f * vv[6][j2] + vv[7][j2]) * wf3;
            Lsu  += vv[2][j2] * wf2 + 2.f * vv[5][j2] * wf3;
            Lsn  += vv[6][j2] * wf3;
            Lssu += vv[5][j2] * wf3;
            L0   += vv[1][j2] * wf1 + (vv[3][j2] + vv[4][j2]) * wf2
                  + (vv[6][j2] + vv[7][j2] + vv[8][j2]) * wf3;
        }
        Lout[0 * 4 + k] = Lu;  Lout[1 * 4 + k] = Ln;   Lout[2 * 4 + k] = Lsu;
        Lout[3 * 4 + k] = Lsn; Lout[4 * 4 + k] = Lssu; Lout[5 * 4 + k] = L0;
    }
}

// ---------------- F: logits -> softmax -> s (f32 out + bf16 side table) --------
__global__ __launch_bounds__(256) void finalk(
    const float2* __restrict__ UN2, const float* __restrict__ SU,
    const float* __restrict__ SN, const float* __restrict__ SSU,
    const float* __restrict__ L,
    float4* __restrict__ sout, ushort4* __restrict__ sbf)
{
    __shared__ float sL[24];
    if (threadIdx.x < 24) sL[threadIdx.x] = L[threadIdx.x];
    __syncthreads();
    int i = blockIdx.x * 256 + threadIdx.x;
    if (i >= NN) return;
    float2 un = UN2[i];
    float u = un.x, n = un.y, su = SU[i], sn = SN[i], ssu = SSU[i];
    float lg[4];
#pragma unroll
    for (int k = 0; k < 4; k++)
        lg[k] = sL[k] * u + sL[4 + k] * n + sL[8 + k] * su
              + sL[12 + k] * sn + sL[16 + k] * ssu + sL[20 + k];
    float mx = fmaxf(fmaxf(lg[0], lg[1]), fmaxf(lg[2], lg[3]));
    float e0 = __expf(lg[0] - mx), e1 = __expf(lg[1] - mx);
    float e2 = __expf(lg[2] - mx), e3 = __expf(lg[3] - mx);
    float inv = 1.f / (e0 + e1 + e2 + e3);
    float s0 = e0 * inv, s1 = e1 * inv, s2 = e2 * inv, s3 = e3 * inv;
    fv4 o = {s0, s1, s2, s3};
    __builtin_nontemporal_store(o, (fv4*)sout + i);
    ushort4 pk; pk.x = f2u(s0); pk.y = f2u(s1); pk.z = f2u(s2); pk.w = f2u(s3);
    sbf[i] = pk;
}

// ---------------- modk: dst-side s in LDS, natural pipelining, NO fence --------
__device__ __forceinline__ void modacc(u64 ua, u64 ub, float we, float* acc) {
    float ax = u2f((unsigned short)ua),         ay = u2f((unsigned short)(ua >> 16));
    float az = u2f((unsigned short)(ua >> 32)), aw = u2f((unsigned short)(ua >> 48));
    float bx = u2f((unsigned short)ub),         by = u2f((unsigned short)(ub >> 16));
    float bz = u2f((unsigned short)(ub >> 32)), bw = u2f((unsigned short)(ub >> 48));
    acc[0] += we;
    acc[1] += we * (ax * bx + ay * by + az * bz + aw * bw);
    acc[2] += we * ax; acc[3] += we * ay;
    acc[4] += we * az; acc[5] += we * aw;
}

__global__ __launch_bounds__(512) void modk(
    const unsigned* __restrict__ pairs, const unsigned short* __restrict__ wp,
    const int* __restrict__ cur, const u64* __restrict__ sbfU,
    float* __restrict__ scal)
{
    __shared__ u64 sS[BSZ];   // 32 KB: this bucket's dst-side s values
    int B = blockIdx.x / M, sl = blockIdx.x % M;
    for (int j = threadIdx.x; j < BSZ; j += 512) {
        int g = (B << BSH) + j;
        sS[j] = (g < NN) ? sbfU[g] : 0ull;
    }
    __syncthreads();
    int b0 = B * CAP;
    int len = cur[B];
    int seg = (((len + M - 1) / M) + 3) & ~3;
    int lo = b0 + sl * seg;
    int hi = lo + seg, e1 = b0 + len;
    if (hi > e1) hi = e1;
    int n = hi - lo;
    float acc[6] = {0, 0, 0, 0, 0, 0};
    if (n > 0) {
        int nq = n >> 2;
        const uv4* pq = (const uv4*)(pairs + lo);
        const u64* wq = (const u64*)(wp + lo);
        for (int i = threadIdx.x; i < nq; i += 1024) {
            uv4 pA = __builtin_nontemporal_load(pq + i);
            u64 wA = __builtin_nontemporal_load(wq + i);
            int iB = i + 512;
            bool vB = iB < nq;
            u64 a0 = sbfU[pA.x & 524287u];
            u64 a1 = sbfU[pA.y & 524287u];
            u64 a2 = sbfU[pA.z & 524287u];
            u64 a3 = sbfU[pA.w & 524287u];
            uv4 pB; u64 wB; u64 a4, a5, a6, a7;
            if (vB) {
                pB = __builtin_nontemporal_load(pq + iB);
                wB = __builtin_nontemporal_load(wq + iB);
                a4 = sbfU[pB.x & 524287u];
                a5 = sbfU[pB.y & 524287u];
                a6 = sbfU[pB.z & 524287u];
                a7 = sbfU[pB.w & 524287u];
            }
            modacc(a0, sS[pA.x >> 19], u2f((unsigned short)wA),         acc);
            modacc(a1, sS[pA.y >> 19], u2f((unsigned short)(wA >> 16)), acc);
            modacc(a2, sS[pA.z >> 19], u2f((unsigned short)(wA >> 32)), acc);
            modacc(a3, sS[pA.w >> 19], u2f((unsigned short)(wA >> 48)), acc);
            if (vB) {
                modacc(a4, sS[pB.x >> 19], u2f((unsigned short)wB),         acc);
                modacc(a5, sS[pB.y >> 19], u2f((unsigned short)(wB >> 16)), acc);
                modacc(a6, sS[pB.z >> 19], u2f((unsigned short)(wB >> 32)), acc);
                modacc(a7, sS[pB.w >> 19], u2f((unsigned short)(wB >> 48)), acc);
            }
        }
        int rem = n & 3;
        if ((int)threadIdx.x < rem) {
            int idx = lo + (nq << 2) + threadIdx.x;
            unsigned p = pairs[idx];
            modacc(sbfU[p & 524287u], sS[p >> 19], u2f(wp[idx]), acc);
        }
    }
    __shared__ float part[8][6];
    int lane = threadIdx.x & 63, wid = threadIdx.x >> 6;
#pragma unroll
    for (int k = 0; k < 6; k++) {
        float r = waveReduceF(acc[k]);
        if (lane == 0) part[wid][k] = r;
    }
    __syncthreads();
    if (threadIdx.x < 6) {
        float vsum = 0.f;
#pragma unroll
        for (int wdi = 0; wdi < 8; wdi++) vsum += part[wdi][threadIdx.x];
        int off = (threadIdx.x == 0) ? 128 : (threadIdx.x == 1 ? 129 : 130 + threadIdx.x);
        atomicAdd(&scal[off], vsum);
    }
}

// ---------------- q ------------------------------------------------------------
__global__ void qk(const float* __restrict__ scal, float* __restrict__ out)
{
    if (threadIdx.x == 0) {
        float inv = 1.f / scal[128];
        float posv = scal[129] * inv;
        float acc = 0.f;
#pragma unroll
        for (int k = 0; k < 4; k++) {
            float d = scal[132 + k] * inv;
            acc += d * d;
        }
        out[(size_t)NN * 4] = posv - acc;
    }
}

extern "C" void kernel_launch(void* const* d_in, const int* in_sizes, int n_in,
                              void* d_out, int out_size, void* d_ws, size_t ws_size,
                              hipStream_t stream) {
    const float* x  = (const float*)d_in[0];
    const int*  ei  = (const int*)d_in[1];
    const int*  src = ei;
    const int*  dst = ei + NE;
    const float* w   = (const float*)d_in[2];
    const float* W1a = (const float*)d_in[3];  const float* b1a = (const float*)d_in[4];
    const float* W1b = (const float*)d_in[5];  const float* b1b = (const float*)d_in[6];
    const float* g1  = (const float*)d_in[7];  const float* be1 = (const float*)d_in[8];
    const float* W2a = (const float*)d_in[9];  const float* b2a = (const float*)d_in[10];
    const float* W2b = (const float*)d_in[11]; const float* b2b = (const float*)d_in[12];
    const float* g2  = (const float*)d_in[13]; const float* be2 = (const float*)d_in[14];
    const float* W3a = (const float*)d_in[15]; const float* b3a = (const float*)d_in[16];
    const float* W3b = (const float*)d_in[17]; const float* b3b = (const float*)d_in[18];
    const float* g3  = (const float*)d_in[19]; const float* be3 = (const float*)d_in[20];
    const float* Wf  = (const float*)d_in[21]; const float* bfb = (const float*)d_in[22];

    // workspace layout:
    //  floats sc[0..1023]: two_m@128, pos@129, ds@132..135, L@160..183,
    //    dm (20 doubles) @ float-idx 384 (byte 1536),
    //    cur ints @ sci[832..954]  (all inside the 4KB memset region)
    //  byte 4096: pairs uint[NB*CAP] (34.3MB) | wp ushort[NB*CAP] (17.1MB) |
    //    slab (32.25MB, u64[NAGG*BSZ] rounds 1/2, float[NAGG*BSZ] round 3) |
    //    UN2 float2[NN] | SU float[NN] | SN float[NN] | SSU float[NN] |
    //    sbf ushort4[NN] | ENC u64[NN]
    float*  sc   = (float*)d_ws;
    int*    sci  = (int*)d_ws;
    double* dm   = (double*)(sc + 384);
    unsigned* pairs = (unsigned*)(sc + 1024);
    unsigned short* wp = (unsigned short*)(pairs + (size_t)NB * CAP);
    float*  slab = (float*)(wp + (size_t)NB * CAP);
    u64*    slabU = (u64*)slab;
    float2* UN2  = (float2*)(slab + (size_t)NAGG * 2 * BSZ);
    float*  SU   = (float*)(UN2 + NN);
    float*  SN   = SU + NN;
    float*  SSU  = SN + NN;
    ushort4* sbf = (ushort4*)(SSU + NN);
    u64*    ENC  = (u64*)(sbf + NN);
    float*  sout = (float*)d_out;

    const int NB_N  = (NN + 255) / 256;
    const int NB_EQ = (NE / 4 + 1023) / 1024;   // 1954 blocks over int4-quads

    hipMemsetAsync(sc, 0, 4096, stream);

    // bucketize once (dst -> 123 fixed-capacity buckets), block counting sort
    scatterk<<<NB_EQ, 512, 0, stream>>>((const iv4*)src, (const iv4*)dst,
                                        (const fv4*)w, sci + 832, pairs, wp);

    // three aggregation rounds; packed u64 atomics in rounds 1/2
    agg1k<<<NAGG, 512, 0, stream>>>(pairs, sci + 832, x, slabU);
    mergeN1<<<NB_N, 256, 0, stream>>>(slabU, x, UN2, ENC);
    agg2k<<<NAGG, 512, 0, stream>>>(pairs, sci + 832, ENC, slabU);
    mergeN2<<<NB_N, 256, 0, stream>>>(slabU, SU, SN);
    agg3k<<<NAGG, 512, 0, stream>>>(pairs, sci + 832, SU, slab);
    m3mom<<<NB_N, 256, 0, stream>>>(slab, UN2, SU, SN, SSU, dm);

    // closed-form logit matrix (1 block, wave-parallel)
    constk<<<1, 64, 0, stream>>>(W1a, b1a, W1b, b1b, g1, be1,
                                 W2a, b2a, W2b, b2b, g2, be2,
                                 W3a, b3a, W3b, b3b, g3, be3,
                                 Wf, bfb, dm, sc + 160);

    // softmax -> modularity -> q (tiny separate kernel; fences are poison)
    finalk<<<NB_N, 256, 0, stream>>>(UN2, SU, SN, SSU, sc + 160, (float4*)sout, sbf);
    modk<<<NAGG, 512, 0, stream>>>(pairs, wp, sci + 832, (const u64*)sbf, sc);
    qk<<<1, 64, 0, stream>>>(sc, sout);
}